// Round 12
// baseline (118.102 us; speedup 1.0000x reference)
//
#include <hip/hip_runtime.h>
#include <hip/hip_bf16.h>
#include <cstdint>
#include <cstddef>

// MHA forward: B=2, T=2048, D=1024, H=16, dk=64. fp32 in/out, bf16 MFMA internal.
#define B_  2
#define T_  2048
#define D_  1024
#define H_  16
#define DK_ 64

typedef __hip_bfloat16 bf16;
typedef __bf16 bf16x8 __attribute__((ext_vector_type(8)));  // MFMA A/B frag (4 VGPRs)
typedef float  f32x4  __attribute__((ext_vector_type(4)));  // MFMA C/D frag

#define MFMA16(a, b, c) __builtin_amdgcn_mfma_f32_16x16x32_bf16((a), (b), (c), 0, 0, 0)

// Q production scale: 1/sqrt(64) * log2(e)  (softmax done in exp2 domain)
#define SCALE_Q 0.1803368801111137f

// fast exp2: raw v_exp_f32 (no denorm fixup; inputs are either ~[-30,8] or -inf-ish)
#if defined(__has_builtin)
#if __has_builtin(__builtin_amdgcn_exp2f)
#define FEXP2(x) __builtin_amdgcn_exp2f(x)
#endif
#endif
#ifndef FEXP2
__device__ static inline float fexp2_asm(float x) {
  float r; asm("v_exp_f32 %0, %1" : "=v"(r) : "v"(x)); return r;
}
#define FEXP2(x) fexp2_asm(x)
#endif

__device__ static inline void gld_lds16(const void* g, void* l) {
  // async global->LDS, 16B per lane; LDS dest is wave-uniform base + lane*16
  __builtin_amdgcn_global_load_lds((const __attribute__((address_space(1))) void*)g,
                                   (__attribute__((address_space(3))) void*)l, 16, 0, 0);
}

__device__ static inline ushort f2bu(float x) {
  union { bf16 h; ushort u; } c;
  c.h = __float2bfloat16(x);
  return c.u;
}

__device__ static inline uint32_t cvtpk_bf16(float lo, float hi) {
  uint32_t r;
  asm volatile("v_cvt_pk_bf16_f32 %0, %1, %2" : "=v"(r) : "v"(lo), "v"(hi));
  return r;  // low16 = bf16(lo), high16 = bf16(hi)
}

// ---------------- pack: x fp32 -> bf16 ----------------
__global__ __launch_bounds__(256) void pack_x_kernel(const float* __restrict__ x,
                                                     bf16* __restrict__ xb) {
  const int i = blockIdx.x * 256 + threadIdx.x;  // exactly 1M threads, 4 elems each
  const float4 v = reinterpret_cast<const float4*>(x)[i];
  union { ushort4 u; bf16 h[4]; } c;
  c.h[0] = __float2bfloat16(v.x);
  c.h[1] = __float2bfloat16(v.y);
  c.h[2] = __float2bfloat16(v.z);
  c.h[3] = __float2bfloat16(v.w);
  reinterpret_cast<ushort4*>(xb)[i] = c.u;
}

// ---------------- pack: W (D,D) fp32 row-major [k][n] -> bf16 transposed [n][k] ----------------
__global__ __launch_bounds__(256) void pack_w_kernel(const float* __restrict__ Wq,
                                                     const float* __restrict__ Wk,
                                                     const float* __restrict__ Wv,
                                                     const float* __restrict__ Wo,
                                                     bf16* __restrict__ Wt,    // [3072][1024]
                                                     bf16* __restrict__ Wot) { // [1024][1024]
  __shared__ bf16 t[64][65];  // +1 pad breaks bank conflicts on transposed read
  const int bid  = blockIdx.x;
  const int mat  = bid >> 8;       // 0..3 : Wq,Wk,Wv,Wo
  const int tile = bid & 255;      // 16x16 tiles of 64x64
  const int tr = tile >> 4, tc = tile & 15;
  const float* W = (mat == 0) ? Wq : (mat == 1) ? Wk : (mat == 2) ? Wv : Wo;
  const int tid = threadIdx.x;
#pragma unroll
  for (int i = 0; i < 16; ++i) {
    const int idx = i * 256 + tid;
    const int r = idx >> 6, c = idx & 63;
    t[r][c] = __float2bfloat16(W[(size_t)(tr * 64 + r) * D_ + tc * 64 + c]);
  }
  __syncthreads();
  bf16* dst = (mat == 3) ? Wot : (Wt + (size_t)mat * D_ * D_);
#pragma unroll
  for (int i = 0; i < 16; ++i) {
    const int idx = i * 256 + tid;
    const int n = idx >> 6, k = idx & 63;
    dst[(size_t)(tc * 64 + n) * D_ + tr * 64 + k] = t[k][n];
  }
}

// ---------------- QKV GEMM: 256x256 tile, BK=64, 8 waves, 4-phase w/ EARLY staging ----------------
// A: [4096][1024] bf16. Bt: [3072][1024] bf16 (B transposed).
// 4 phases per K-tile, one C-quadrant each. Tile t+1's stages issued EARLY:
// A halves in phase 0, B halves in phase 1 (8 loads total); the single vmcnt(0)
// at the end of phase 3 then has ~2-3 phases of slack to cover load latency.
// No __syncthreads in the loop. LDS tiles [128 rows][8 chunks of 16B], chunk c at
// slot c^(r&7) (T2; pre-swizzled src). T1 XCD swizzle over 192 blocks.
// Epilogue: Qb/Kb [BH][T][64], Vt [BH][64][T], + bias.
__global__ __launch_bounds__(512, 2) void gemm_qkv_kernel(
    const bf16* __restrict__ A, const bf16* __restrict__ Bt,
    const float* __restrict__ bias0, const float* __restrict__ bias1,
    const float* __restrict__ bias2,
    bf16* __restrict__ Qb, bf16* __restrict__ Kb, bf16* __restrict__ Vt) {
  __shared__ __align__(16) bf16 Asm[2][2][128 * 64];  // [dbuf][half][r][chunk] 64 KB
  __shared__ __align__(16) bf16 Bsm[2][2][128 * 64];  // 64 KB
  const int tid = threadIdx.x, lane = tid & 63, wid = tid >> 6;
  const int l15 = lane & 15, lhi = lane >> 4;
  const int wm = wid >> 2, wn = wid & 3;

  // T1: XCD-contiguous remap of the 192-block grid (16M x 12N), 192 % 8 == 0
  const int flat = blockIdx.x + blockIdx.y * 12;
  const int swz = (flat & 7) * 24 + (flat >> 3);
  const int mbase = (swz / 12) * 256;
  const int nbase = (swz % 12) * 256;

  // hoisted per-thread staging sources (chunk idx it*512+tid; r=idx>>3, c=idx&7, cs=c^(r&7))
  const int i0 = tid, i1 = 512 + tid;
  const int r0 = i0 >> 3, cs0 = ((i0 & 7) ^ (r0 & 7)) * 8;
  const int r1 = i1 >> 3, cs1 = ((i1 & 7) ^ (r1 & 7)) * 8;
  const bf16* spA00 = A  + (size_t)(mbase +       r0) * D_ + cs0;
  const bf16* spA01 = A  + (size_t)(mbase +       r1) * D_ + cs1;
  const bf16* spA10 = A  + (size_t)(mbase + 128 + r0) * D_ + cs0;
  const bf16* spA11 = A  + (size_t)(mbase + 128 + r1) * D_ + cs1;
  const bf16* spB00 = Bt + (size_t)(nbase +       r0) * D_ + cs0;
  const bf16* spB01 = Bt + (size_t)(nbase +       r1) * D_ + cs1;
  const bf16* spB10 = Bt + (size_t)(nbase + 128 + r0) * D_ + cs0;
  const bf16* spB11 = Bt + (size_t)(nbase + 128 + r1) * D_ + cs1;
  const int ub0 = wid * 1024;          // wave-uniform LDS byte base, chunk set 0
  const int ub1 = 8192 + wid * 1024;   // chunk set 1

  f32x4 acc[8][4] = {};

  // prologue: stage K-tile 0 (all 4 halves), full drain, barrier
  gld_lds16(spA00, (char*)Asm[0][0] + ub0); gld_lds16(spA01, (char*)Asm[0][0] + ub1);
  gld_lds16(spA10, (char*)Asm[0][1] + ub0); gld_lds16(spA11, (char*)Asm[0][1] + ub1);
  gld_lds16(spB00, (char*)Bsm[0][0] + ub0); gld_lds16(spB01, (char*)Bsm[0][0] + ub1);
  gld_lds16(spB10, (char*)Bsm[0][1] + ub0); gld_lds16(spB11, (char*)Bsm[0][1] + ub1);
  asm volatile("s_waitcnt vmcnt(0)" ::: "memory");
  __builtin_amdgcn_s_barrier();

#define PHASE(db, mh, nh, STAGE_CODE, DO_VM)                                             \
  {                                                                                      \
    const char* Ah = (const char*)Asm[db][wm];                                           \
    const char* Bh = (const char*)Bsm[db][wn >> 1];                                      \
    bf16x8 afr[4][2], bfr[2][2];                                                         \
    _Pragma("unroll") for (int m4 = 0; m4 < 4; ++m4)                                     \
      _Pragma("unroll") for (int kk = 0; kk < 2; ++kk)                                   \
        afr[m4][kk] = *reinterpret_cast<const bf16x8*>(                                  \
            Ah + ((mh) * 64 + m4 * 16 + l15) * 128 + (((kk * 4 + lhi) ^ (l15 & 7)) * 16)); \
    _Pragma("unroll") for (int n2 = 0; n2 < 2; ++n2)                                     \
      _Pragma("unroll") for (int kk = 0; kk < 2; ++kk)                                   \
        bfr[n2][kk] = *reinterpret_cast<const bf16x8*>(                                  \
            Bh + ((wn & 1) * 64 + ((nh) * 2 + n2) * 16 + l15) * 128 +                    \
                 (((kk * 4 + lhi) ^ (l15 & 7)) * 16));                                   \
    STAGE_CODE                                                                           \
    __builtin_amdgcn_s_barrier();                                                        \
    asm volatile("s_waitcnt lgkmcnt(0)" ::: "memory");                                   \
    __builtin_amdgcn_sched_barrier(0);                                                   \
    __builtin_amdgcn_s_setprio(1);                                                       \
    _Pragma("unroll") for (int n2 = 0; n2 < 2; ++n2)                                     \
      _Pragma("unroll") for (int m4 = 0; m4 < 4; ++m4)                                   \
        _Pragma("unroll") for (int kk = 0; kk < 2; ++kk)                                 \
          acc[(mh) * 4 + m4][(nh) * 2 + n2] =                                            \
              MFMA16(afr[m4][kk], bfr[n2][kk], acc[(mh) * 4 + m4][(nh) * 2 + n2]);       \
    __builtin_amdgcn_s_setprio(0);                                                       \
    if (DO_VM) asm volatile("s_waitcnt vmcnt(0)" ::: "memory");                          \
    __builtin_amdgcn_s_barrier();                                                        \
  }

  for (int t = 0; t < 16; ++t) {
    const int db = t & 1, nb = db ^ 1;
    const bool st = (t < 15);
    const int ko = (t + 1) * 64;
    // phase 0: stage BOTH A halves of tile t+1 (early issue -> 3 phases of slack)
    PHASE(db, 0, 0,
          if (st) {
            gld_lds16(spA00 + ko, (char*)Asm[nb][0] + ub0);
            gld_lds16(spA01 + ko, (char*)Asm[nb][0] + ub1);
            gld_lds16(spA10 + ko, (char*)Asm[nb][1] + ub0);
            gld_lds16(spA11 + ko, (char*)Asm[nb][1] + ub1);
          },
          false);
    // phase 1: stage BOTH B halves of tile t+1 (2 phases of slack)
    PHASE(db, 1, 0,
          if (st) {
            gld_lds16(spB00 + ko, (char*)Bsm[nb][0] + ub0);
            gld_lds16(spB01 + ko, (char*)Bsm[nb][0] + ub1);
            gld_lds16(spB10 + ko, (char*)Bsm[nb][1] + ub0);
            gld_lds16(spB11 + ko, (char*)Bsm[nb][1] + ub1);
          },
          false);
    // phases 2,3: compute only; single counted drain at the end of phase 3
    PHASE(db, 0, 1, {}, false);
    PHASE(db, 1, 1, {}, true);
  }
#undef PHASE

  // epilogue: C layout col = l15 (n-side), row = lhi*4 + j (m-side)
  const int seg = nbase >> 10;  // uniform per block (256 | 1024)
  const float* bias = (seg == 0) ? bias0 : (seg == 1) ? bias1 : bias2;
#pragma unroll
  for (int nf = 0; nf < 4; ++nf) {
    const int col  = nbase + wn * 64 + nf * 16 + l15;
    const int ncol = col & 1023;
    const float bv_ = bias[ncol];
    const int h = ncol >> 6, dk = ncol & 63;
    if (seg == 2) {
      // V: pack 4 consecutive t (j=0..3) into one 8B store
#pragma unroll
      for (int mf = 0; mf < 8; ++mf) {
        const int t0 = mbase + wm * 128 + mf * 16 + lhi * 4;  // multiple of 4
        const int b = t0 >> 11, t = t0 & 2047;
        union { ushort u[4]; uint2 v; } pk;
#pragma unroll
        for (int j = 0; j < 4; ++j) pk.u[j] = f2bu(acc[mf][nf][j] + bv_);
        *reinterpret_cast<uint2*>(&Vt[((size_t)(b * H_ + h) * DK_ + dk) * T_ + t]) = pk.v;
      }
    } else {
#pragma unroll
      for (int mf = 0; mf < 8; ++mf) {
#pragma unroll
        for (int j = 0; j < 4; ++j) {
          const int row = mbase + wm * 128 + mf * 16 + lhi * 4 + j;
          const int b = row >> 11, t = row & 2047;
          const int bh = b * H_ + h;
          float outv = acc[mf][nf][j] + bv_;
          if (seg == 0) outv *= SCALE_Q;  // fold 1/sqrt(dk)*log2(e) into Q
          const bf16 hv = __float2bfloat16(outv);
          if (seg == 0) Qb[((size_t)bh * T_ + t) * DK_ + dk] = hv;
          else          Kb[((size_t)bh * T_ + t) * DK_ + dk] = hv;
        }
      }
    }
  }
}

// ---------------- out GEMM: 128x64 tile, BK=32, 4 waves (2x2 of 64x32) ----------------
// out[4096][1024] = A @ Wot^T + bias ; grid (16, 32) = 512 blocks -> 2 blocks/CU.
__global__ __launch_bounds__(256, 2) void gemm_out_kernel(
    const bf16* __restrict__ A, const bf16* __restrict__ Bt,
    const float* __restrict__ bias, float* __restrict__ outp) {
  __shared__ bf16 As[128 * 32];
  __shared__ bf16 Bs[64 * 32];
  const int tid  = threadIdx.x;
  const int lane = tid & 63, wid = tid >> 6;
  const int wr = wid >> 1, wc = wid & 1;
  const int l15 = lane & 15, lhi = lane >> 4;
  const int mbase = blockIdx.y * 128, nbase = blockIdx.x * 64;

  f32x4 acc[4][2] = {};

  const int r0  = tid >> 2;
  const int kc0 = (tid & 3) * 8;
  char* AsB = (char*)As;
  char* BsB = (char*)Bs;

  for (int kt = 0; kt < D_; kt += 32) {
    gld_lds16(A  + (size_t)(mbase + r0)      * D_ + kt + kc0, AsB + wid * 1024);
    gld_lds16(A  + (size_t)(mbase + 64 + r0) * D_ + kt + kc0, AsB + 4096 + wid * 1024);
    gld_lds16(Bt + (size_t)(nbase + r0)      * D_ + kt + kc0, BsB + wid * 1024);
    __syncthreads();

    bf16x8 af[4], bfv[2];
#pragma unroll
    for (int m = 0; m < 4; ++m)
      af[m] = *reinterpret_cast<const bf16x8*>(&As[(wr * 64 + m * 16 + l15) * 32 + lhi * 8]);
#pragma unroll
    for (int n = 0; n < 2; ++n)
      bfv[n] = *reinterpret_cast<const bf16x8*>(&Bs[(wc * 32 + n * 16 + l15) * 32 + lhi * 8]);
#pragma unroll
    for (int m = 0; m < 4; ++m)
#pragma unroll
      for (int n = 0; n < 2; ++n)
        acc[m][n] = MFMA16(af[m], bfv[n], acc[m][n]);
    __syncthreads();
  }

#pragma unroll
  for (int n = 0; n < 2; ++n) {
    const int col = nbase + wc * 32 + n * 16 + l15;
    const float bv_ = bias[col];
#pragma unroll
    for (int m = 0; m < 4; ++m)
#pragma unroll
      for (int j = 0; j < 4; ++j) {
        const int row = mbase + wr * 64 + m * 16 + lhi * 4 + j;
        outp[(size_t)row * D_ + col] = acc[m][n][j] + bv_;
      }
  }
}

// ---------------- flash attention (causal): 8-wave blocks, KV=128 per round ----------------
// Block = 8 waves (512 thr). Intra-block causal pairing: waves 0-3 own q-tile p,
// waves 4-7 own q-tile 31-p (64-row tiles) -> uniform live work per SIMD under any
// block->CU mapping. Each round stages a 128-wide K/V slab (two 64-kv sub-tiles).
// Staging addresses HOISTED; softmax exp2 via raw v_exp_f32; defer-max (T13, THR=8).
// SWAPPED S^T = mfma(K,Q); P A-fragments built in registers (cvt_pk + shfl_xor(16)),
// kv-chunk permutation pi(lhi)=bitswap applied to P and V fragments.
// K LDS [128 rows][8 chunks] slot c^(r&7); V LDS [64 rows][16 chunks] slot c^(r&15).
__global__ __launch_bounds__(512, 4) void attn_kernel(const bf16* __restrict__ Q,
                                                      const bf16* __restrict__ Kg,
                                                      const bf16* __restrict__ Vt,
                                                      bf16* __restrict__ Mg) {
  __shared__ __align__(16) bf16 Kl[2][128 * 64];
  __shared__ __align__(16) bf16 Vl[2][64 * 128];
  const int tid = threadIdx.x, lane = tid & 63, wid = tid >> 6;
  const int l15 = lane & 15, lhi = lane >> 4;
  const int p  = blockIdx.x & 15;             // complementary q-tile pair index
  const int bh = blockIdx.x >> 4;             // adjacent bids share bh -> K/V L2 locality
  const int half = wid >> 2, w4 = wid & 3;
  const int qtile = half ? (31 - p) : p;
  const int qbase = qtile * 64 + w4 * 16;
  const int b = bh >> 4, h = bh & 15;

  const bf16* Qp = Q  + (size_t)bh * T_ * DK_;
  const bf16* Kp = Kg + (size_t)bh * T_ * DK_;
  const bf16* Vp = Vt + (size_t)bh * DK_ * T_;

  const bf16x8 qf0 = *reinterpret_cast<const bf16x8*>(&Qp[(size_t)(qbase + l15) * DK_ + lhi * 8]);
  const bf16x8 qf1 = *reinterpret_cast<const bf16x8*>(&Qp[(size_t)(qbase + l15) * DK_ + 32 + lhi * 8]);

  bf16x8 onesb;
#pragma unroll
  for (int i = 0; i < 8; ++i) onesb[i] = (__bf16)1.0f;

  f32x4 o[4] = {};
  f32x4 lacc = {};
  float mrow = -1e30f;  // running max for this lane's q-row (q = qbase + l15)

  const int ntr = (33 - p) >> 1;  // 128-wide rounds covering high tile's causal extent

  // hoisted per-thread staging sources (T2 pre-swizzle folded in once)
  const int iA = tid, iB = 512 + tid;
  const bf16* ks0 = Kp + (size_t)(iA >> 3) * DK_ + (((iA & 7) ^ ((iA >> 3) & 7)) * 8);
  const bf16* ks1 = Kp + (size_t)(iB >> 3) * DK_ + (((iB & 7) ^ ((iB >> 3) & 7)) * 8);
  const bf16* vs0 = Vp + (size_t)(iA >> 4) * T_ + (((iA & 15) ^ ((iA >> 4) & 15)) * 8);
  const bf16* vs1 = Vp + (size_t)(iB >> 4) * T_ + (((iB & 15) ^ ((iB >> 4) & 15)) * 8);
  const int ub0 = wid * 1024;           // wave-uniform LDS byte base, it=0
  const int ub1 = 8192 + wid * 1024;    // it=1

  // stage round 0 into buffer 0
  gld_lds16(ks0, (char*)Kl[0] + ub0);
  gld_lds16(ks1, (char*)Kl[0] + ub1);
  gld_lds16(vs0, (char*)Vl[0] + ub0);
  gld_lds16(vs1, (char*)Vl[0] + ub1);
  ks0 += 128 * DK_; ks1 += 128 * DK_; vs0 += 128; vs1 += 128;
  __syncthreads();

  for (int rnd = 0; rnd < ntr; ++rnd) {
    const int cur = rnd & 1;
    const char* Kb_ = cur ? (const char*)Kl[1] : (const char*)Kl[0];
    const char* Vb_ = cur ? (const char*)Vl[1] : (const char*)Vl[0];
    if (rnd + 1 < ntr) {  // stage next slab into the other buffer
      char* Kn = cur ? (char*)Kl[0] : (char*)Kl[1];
      char* Vn = cur ? (char*)Vl[0] : (char*)Vl[1];
      gld_lds16(ks0, Kn + ub0);
      gld_lds16(ks1, Kn + ub1);
      gld_lds16(vs0, Vn + ub0);
      gld_lds16(vs1, Vn + ub1);
      ks0 += 128 * DK_; ks1 += 128 * DK_; vs0 += 128; vs1 += 128;
    }

#pragma unroll
    for (int sub = 0; sub < 2; ++sub) {
      const int kv0 = rnd * 128 + sub * 64;
      if (kv0 <= qbase + 15) {  // wave-uniform: wave has live columns in this sub-tile
        // ---- S^T = K Q^T : lane holds q=l15; rows kv = kv0 + s*16 + lhi*4 + j
        f32x4 sv[4];
#pragma unroll
        for (int s = 0; s < 4; ++s) {
          const int cbase = kv0 + s * 16;
          if (cbase <= qbase + 15) {
            const int row = sub * 64 + s * 16 + l15;  // row & 7 == l15 & 7
            const int rsw = l15 & 7;
            const bf16x8 k0 = *reinterpret_cast<const bf16x8*>(Kb_ + row * 128 + ((lhi       ^ rsw) * 16));
            const bf16x8 k1 = *reinterpret_cast<const bf16x8*>(Kb_ + row * 128 + (((4 + lhi) ^ rsw) * 16));
            f32x4 z = {};
            z = MFMA16(k0, qf0, z);          // swapped operand order
            sv[s] = MFMA16(k1, qf1, z);
          } else {
#pragma unroll
            for (int j = 0; j < 4; ++j) sv[s][j] = -1e30f;
          }
        }

        // ---- causal mask (kv = row, q = col): only the diagonal-straddling s-tile
#pragma unroll
        for (int s = 0; s < 4; ++s) {
          const int cbase = kv0 + s * 16;
          if (cbase <= qbase + 15 && cbase + 15 > qbase) {
            const int r = qbase + l15;
#pragma unroll
            for (int j = 0; j < 4; ++j) {
              const int c = cbase + lhi * 4 + j;
              sv[s][j] = (c <= r) ? sv[s][j] : -1e30f;
            }
          }
        }

        // ---- online softmax (exp2 domain), defer-max (T13): in-lane max only
        float ml = sv[0][0];
#pragma unroll
        for (int s = 0; s < 4; ++s)
#pragma unroll
          for (int j = 0; j < 4; ++j) ml = fmaxf(ml, sv[s][j]);

        if (__any(ml > mrow + 8.0f)) {
          float mx = ml;
          mx = fmaxf(mx, __shfl_xor(mx, 16, 64));
          mx = fmaxf(mx, __shfl_xor(mx, 32, 64));
          const float mn = fmaxf(mrow, mx);
          const float sc = FEXP2(mrow - mn);
          mrow = mn;
          // broadcast sc into O-layout rows: row q' = lhi*4 + j lives in lane q'
          const int sci = __float_as_int(sc);
#pragma unroll
          for (int j = 0; j < 4; ++j) {
            const float scj = __int_as_float(
                __builtin_amdgcn_ds_bpermute((lhi * 4 + j) * 4, sci));
            lacc[j] *= scj;
            o[0][j] *= scj; o[1][j] *= scj; o[2][j] *= scj; o[3][j] *= scj;
          }
        }
#pragma unroll
        for (int s = 0; s < 4; ++s)
#pragma unroll
          for (int j = 0; j < 4; ++j) sv[s][j] = FEXP2(sv[s][j] - mrow);

        // ---- P A-fragments in registers (no LDS round-trip).
        // Lane's k-slot chunk holds kv chunk pi(lhi), pi = [0,2,1,3] (bitswap).
        const bool oddl = (lhi & 1) != 0;
        bf16x8 pf[2];
#pragma unroll
        for (int hh = 0; hh < 2; ++hh) {
          const uint32_t u0l = cvtpk_bf16(sv[2 * hh][0], sv[2 * hh][1]);
          const uint32_t u0h = cvtpk_bf16(sv[2 * hh][2], sv[2 * hh][3]);
          const uint32_t u1l = cvtpk_bf16(sv[2 * hh + 1][0], sv[2 * hh + 1][1]);
          const uint32_t u1h = cvtpk_bf16(sv[2 * hh + 1][2], sv[2 * hh + 1][3]);
          const uint32_t sl = oddl ? u0l : u1l;
          const uint32_t sh = oddl ? u0h : u1h;
          const uint32_t rl = (uint32_t)__shfl_xor((int)sl, 16, 64);
          const uint32_t rh = (uint32_t)__shfl_xor((int)sh, 16, 64);
          union { uint32_t w[4]; bf16x8 v; } fr;
          fr.w[0] = oddl ? rl : u0l;
          fr.w[1] = oddl ? rh : u0h;
          fr.w[2] = oddl ? u1l : rl;
          fr.w[3] = oddl ? u1h : rh;
          pf[hh] = fr.v;
        }

        // ---- V fragments from LDS with the same kv-chunk permutation pi(lhi)
        const int pl = ((lhi & 1) << 1) | (lhi >> 1);
        bf16x8 vf[8];
#pragma unroll
        for (int d = 0; d < 4; ++d) {
          const int rowv = d * 16 + l15;  // rowv & 15 == l15
#pragma unroll
          for (int s2 = 0; s2 < 2; ++s2) {
            const int cread = sub * 8 + s2 * 4 + pl;
            vf[d * 2 + s2] = *reinterpret_cast<const bf16x8*>(
                Vb_ + rowv * 256 + ((cread ^ l15) * 16));
          }
        }

        // ---- O += P V ; row-sums l += P 1 (same C layout & rescale as O)
#pragma unroll
        for (int d = 0; d < 4; ++d) {
          o[d] = MFMA16(pf[0], vf[d * 2 + 0], o[d]);
          o[d] = MFMA16(pf[1], vf[d * 2 + 1], o[d]);
        }
        lacc = MFMA16(pf[0], onesb, lacc);
        lacc = MFMA16(pf[1], onesb, lacc);
      }
    }

    __syncthreads();  // drains vmcnt (next slab staged) + orders buffer reuse
  }

#pragma unroll
  for (int j = 0; j < 4; ++j) {
    const float inv = 1.0f / lacc[j];
    const int tq = qbase + lhi * 4 + j;
#pragma unroll
    for (int d = 0; d < 4; ++d)
      Mg[((size_t)b * T_ + tq) * D_ + h * DK_ + d * 16 + l15] = __float2bfloat16(o[d][j] * inv);
  }
}

// ---------------- launch ----------------
extern "C" void kernel_launch(void* const* d_in, const int* in_sizes, int n_in,
                              void* d_out, int out_size, void* d_ws, size_t ws_size,
                              hipStream_t stream) {
  (void)in_sizes; (void)n_in; (void)out_size; (void)ws_size;
  const float* x  = (const float*)d_in[0];
  const float* Wq = (const float*)d_in[1];
  const float* bq = (const float*)d_in[2];
  const float* Wk = (const float*)d_in[3];
  const float* bk = (const float*)d_in[4];
  const float* Wv = (const float*)d_in[5];
  const float* bv = (const float*)d_in[6];
  const float* Wo = (const float*)d_in[7];
  const float* bo = (const float*)d_in[8];
  float* out = (float*)d_out;

  // workspace layout (40 MB): Mg aliases xb (xb dead after QKV GEMM, attn runs after)
  char* ws = (char*)d_ws;
  bf16* xb  = (bf16*)(ws);                       // 8 MB [4096][1024]
  bf16* Mg  = (bf16*)(ws);                       // 8 MB [4096][1024] (alias, written by attn)
  bf16* Wt  = (bf16*)(ws + (size_t)( 8u << 20)); // 6 MB [3072][1024] (Wq|Wk|Wv transposed)
  bf16* Wot = (bf16*)(ws + (size_t)(14u << 20)); // 2 MB [1024][1024] (Wo transposed)
  bf16* Qb  = (bf16*)(ws + (size_t)(16u << 20)); // 8 MB [32][2048][64]
  bf16* Kb  = (bf16*)(ws + (size_t)(24u << 20)); // 8 MB [32][2048][64]
  bf16* Vt  = (bf16*)(ws + (size_t)(32u << 20)); // 8 MB [32][64][2048]

  pack_x_kernel<<<4096, 256, 0, stream>>>(x, xb);
  pack_w_kernel<<<1024, 256, 0, stream>>>(Wq, Wk, Wv, Wo, Wt, Wot);
  // fused QKV: C[4096][3072] = xb @ [Wq|Wk|Wv], 256x256 4-phase early-stage
  gemm_qkv_kernel<<<dim3(12, 16), 512, 0, stream>>>(xb, Wt, bq, bk, bv, Qb, Kb, Vt);
  attn_kernel<<<dim3(512), 512, 0, stream>>>(Qb, Kb, Vt, Mg);
  // out[4096][1024] = Mg @ Wo + bo
  gemm_out_kernel<<<dim3(16, 32), 256, 0, stream>>>(Mg, Wot, bo, out);
}

// Round 13
// 108.004 us; speedup vs baseline: 1.0935x; 1.0935x over previous
//
#include <hip/hip_runtime.h>
#include <hip/hip_bf16.h>
#include <cstdint>
#include <cstddef>

// MHA forward: B=2, T=2048, D=1024, H=16, dk=64. fp32 in/out, bf16 MFMA internal.
#define B_  2
#define T_  2048
#define D_  1024
#define H_  16
#define DK_ 64

typedef __hip_bfloat16 bf16;
typedef __bf16 bf16x8 __attribute__((ext_vector_type(8)));  // MFMA A/B frag (4 VGPRs)
typedef float  f32x4  __attribute__((ext_vector_type(4)));  // MFMA C/D frag

#define MFMA16(a, b, c) __builtin_amdgcn_mfma_f32_16x16x32_bf16((a), (b), (c), 0, 0, 0)

// Q production scale: 1/sqrt(64) * log2(e)  (softmax done in exp2 domain)
#define SCALE_Q 0.1803368801111137f

// fast exp2: raw v_exp_f32 (no denorm fixup; inputs are either ~[-30,8] or -inf-ish)
#if defined(__has_builtin)
#if __has_builtin(__builtin_amdgcn_exp2f)
#define FEXP2(x) __builtin_amdgcn_exp2f(x)
#endif
#endif
#ifndef FEXP2
__device__ static inline float fexp2_asm(float x) {
  float r; asm("v_exp_f32 %0, %1" : "=v"(r) : "v"(x)); return r;
}
#define FEXP2(x) fexp2_asm(x)
#endif

__device__ static inline void gld_lds16(const void* g, void* l) {
  // async global->LDS, 16B per lane; LDS dest is wave-uniform base + lane*16
  __builtin_amdgcn_global_load_lds((const __attribute__((address_space(1))) void*)g,
                                   (__attribute__((address_space(3))) void*)l, 16, 0, 0);
}

__device__ static inline ushort f2bu(float x) {
  union { bf16 h; ushort u; } c;
  c.h = __float2bfloat16(x);
  return c.u;
}

__device__ static inline uint32_t cvtpk_bf16(float lo, float hi) {
  uint32_t r;
  asm volatile("v_cvt_pk_bf16_f32 %0, %1, %2" : "=v"(r) : "v"(lo), "v"(hi));
  return r;  // low16 = bf16(lo), high16 = bf16(hi)
}

// ---------------- fused pack: x fp32->bf16 (bids 0..4095) + W transpose (bids 4096..5119) ----------------
__global__ __launch_bounds__(256) void pack_all_kernel(const float* __restrict__ x,
                                                       const float* __restrict__ Wq,
                                                       const float* __restrict__ Wk,
                                                       const float* __restrict__ Wv,
                                                       const float* __restrict__ Wo,
                                                       bf16* __restrict__ xb,
                                                       bf16* __restrict__ Wt,    // [3072][1024]
                                                       bf16* __restrict__ Wot) { // [1024][1024]
  __shared__ bf16 t[64][65];  // +1 pad breaks bank conflicts on transposed read
  const int bid = blockIdx.x;
  const int tid = threadIdx.x;
  if (bid < 4096) {
    // ---- pack x: 4 fp32 -> 4 bf16 per thread
    const int i = bid * 256 + tid;
    const float4 v = reinterpret_cast<const float4*>(x)[i];
    union { ushort4 u; bf16 h[4]; } c;
    c.h[0] = __float2bfloat16(v.x);
    c.h[1] = __float2bfloat16(v.y);
    c.h[2] = __float2bfloat16(v.z);
    c.h[3] = __float2bfloat16(v.w);
    reinterpret_cast<ushort4*>(xb)[i] = c.u;
    return;
  }
  // ---- pack W: transpose+convert 64x64 tiles
  const int wb  = bid - 4096;
  const int mat  = wb >> 8;        // 0..3 : Wq,Wk,Wv,Wo
  const int tile = wb & 255;       // 16x16 tiles of 64x64
  const int tr = tile >> 4, tc = tile & 15;
  const float* W = (mat == 0) ? Wq : (mat == 1) ? Wk : (mat == 2) ? Wv : Wo;
#pragma unroll
  for (int i = 0; i < 16; ++i) {
    const int idx = i * 256 + tid;
    const int r = idx >> 6, c = idx & 63;
    t[r][c] = __float2bfloat16(W[(size_t)(tr * 64 + r) * D_ + tc * 64 + c]);
  }
  __syncthreads();
  bf16* dst = (mat == 3) ? Wot : (Wt + (size_t)mat * D_ * D_);
#pragma unroll
  for (int i = 0; i < 16; ++i) {
    const int idx = i * 256 + tid;
    const int n = idx >> 6, k = idx & 63;
    dst[(size_t)(tc * 64 + n) * D_ + tr * 64 + k] = t[k][n];
  }
}

// ---------------- QKV GEMM: 128x128 bf16, BK=32, 4 waves (2x2 of 64x64) ----------------
// A: [M][K] row-major bf16.  Bt: [N][K] row-major bf16 (i.e. B transposed).
// Epilogue -> Qb/Kb [BH][T][64], Vt [BH][64][T] (V packed 4t/store), + bias;
// Q scaled by SCALE_Q.
__global__ __launch_bounds__(256, 3) void gemm_qkv_kernel(
    const bf16* __restrict__ A, const bf16* __restrict__ Bt,
    const float* __restrict__ bias0, const float* __restrict__ bias1,
    const float* __restrict__ bias2,
    bf16* __restrict__ Qb, bf16* __restrict__ Kb, bf16* __restrict__ Vt) {
  __shared__ bf16 As[128 * 32];
  __shared__ bf16 Bs[128 * 32];
  const int tid  = threadIdx.x;
  const int lane = tid & 63, wid = tid >> 6;
  const int wr = wid >> 1, wc = wid & 1;
  const int l15 = lane & 15, lhi = lane >> 4;
  const int mbase = blockIdx.y * 128, nbase = blockIdx.x * 128;

  f32x4 acc[4][4] = {};

  const int r0  = tid >> 2;        // staged row for chunk p=0 (p=1 is +64)
  const int kc0 = (tid & 3) * 8;   // k offset within BK
  char* AsB = (char*)As;
  char* BsB = (char*)Bs;

  for (int kt = 0; kt < D_; kt += 32) {
    gld_lds16(A  + (size_t)(mbase + r0)      * D_ + kt + kc0, AsB + wid * 1024);
    gld_lds16(A  + (size_t)(mbase + 64 + r0) * D_ + kt + kc0, AsB + 4096 + wid * 1024);
    gld_lds16(Bt + (size_t)(nbase + r0)      * D_ + kt + kc0, BsB + wid * 1024);
    gld_lds16(Bt + (size_t)(nbase + 64 + r0) * D_ + kt + kc0, BsB + 4096 + wid * 1024);
    __syncthreads();  // compiler drains vmcnt before barrier

    bf16x8 af[4], bfv[4];
#pragma unroll
    for (int m = 0; m < 4; ++m)
      af[m] = *reinterpret_cast<const bf16x8*>(&As[(wr * 64 + m * 16 + l15) * 32 + lhi * 8]);
#pragma unroll
    for (int n = 0; n < 4; ++n)
      bfv[n] = *reinterpret_cast<const bf16x8*>(&Bs[(wc * 64 + n * 16 + l15) * 32 + lhi * 8]);
#pragma unroll
    for (int m = 0; m < 4; ++m)
#pragma unroll
      for (int n = 0; n < 4; ++n)
        acc[m][n] = MFMA16(af[m], bfv[n], acc[m][n]);
    __syncthreads();
  }

  // epilogue: D layout col = lane&15, row = (lane>>4)*4 + j
#pragma unroll
  for (int n = 0; n < 4; ++n) {
    const int col = nbase + wc * 64 + n * 16 + l15;
    const int seg  = col >> 10;      // 0=Q 1=K 2=V (uniform per block)
    const int ncol = col & 1023;
    const float* bias = (seg == 0) ? bias0 : (seg == 1) ? bias1 : bias2;
    const float bv_ = bias[ncol];
    const int h = ncol >> 6, dk = ncol & 63;
    if (seg == 2) {
      // V: pack 4 consecutive t (j=0..3) into one 8B store
#pragma unroll
      for (int m = 0; m < 4; ++m) {
        const int t0 = mbase + wr * 64 + m * 16 + lhi * 4;  // multiple of 4
        const int b = t0 >> 11, t = t0 & 2047;
        union { ushort u[4]; uint2 v; } pk;
#pragma unroll
        for (int j = 0; j < 4; ++j) pk.u[j] = f2bu(acc[m][n][j] + bv_);
        *reinterpret_cast<uint2*>(&Vt[((size_t)(b * H_ + h) * DK_ + dk) * T_ + t]) = pk.v;
      }
    } else {
#pragma unroll
      for (int m = 0; m < 4; ++m) {
#pragma unroll
        for (int j = 0; j < 4; ++j) {
          const int row = mbase + wr * 64 + m * 16 + lhi * 4 + j;
          const int b = row >> 11, t = row & 2047;
          const int bh = b * H_ + h;
          float outv = acc[m][n][j] + bv_;
          if (seg == 0) outv *= SCALE_Q;  // fold 1/sqrt(dk)*log2(e) into Q
          const bf16 hv = __float2bfloat16(outv);
          if (seg == 0) Qb[((size_t)bh * T_ + t) * DK_ + dk] = hv;
          else          Kb[((size_t)bh * T_ + t) * DK_ + dk] = hv;
        }
      }
    }
  }
}

// ---------------- out GEMM: 128x64 tile, BK=32, 4 waves (2x2 of 64x32) ----------------
// out[4096][1024] = A @ Wot^T + bias ; grid (16, 32) = 512 blocks -> 2 blocks/CU.
__global__ __launch_bounds__(256, 2) void gemm_out_kernel(
    const bf16* __restrict__ A, const bf16* __restrict__ Bt,
    const float* __restrict__ bias, float* __restrict__ outp) {
  __shared__ bf16 As[128 * 32];
  __shared__ bf16 Bs[64 * 32];
  const int tid  = threadIdx.x;
  const int lane = tid & 63, wid = tid >> 6;
  const int wr = wid >> 1, wc = wid & 1;
  const int l15 = lane & 15, lhi = lane >> 4;
  const int mbase = blockIdx.y * 128, nbase = blockIdx.x * 64;

  f32x4 acc[4][2] = {};

  const int r0  = tid >> 2;
  const int kc0 = (tid & 3) * 8;
  char* AsB = (char*)As;
  char* BsB = (char*)Bs;

  for (int kt = 0; kt < D_; kt += 32) {
    gld_lds16(A  + (size_t)(mbase + r0)      * D_ + kt + kc0, AsB + wid * 1024);
    gld_lds16(A  + (size_t)(mbase + 64 + r0) * D_ + kt + kc0, AsB + 4096 + wid * 1024);
    gld_lds16(Bt + (size_t)(nbase + r0)      * D_ + kt + kc0, BsB + wid * 1024);
    __syncthreads();

    bf16x8 af[4], bfv[2];
#pragma unroll
    for (int m = 0; m < 4; ++m)
      af[m] = *reinterpret_cast<const bf16x8*>(&As[(wr * 64 + m * 16 + l15) * 32 + lhi * 8]);
#pragma unroll
    for (int n = 0; n < 2; ++n)
      bfv[n] = *reinterpret_cast<const bf16x8*>(&Bs[(wc * 32 + n * 16 + l15) * 32 + lhi * 8]);
#pragma unroll
    for (int m = 0; m < 4; ++m)
#pragma unroll
      for (int n = 0; n < 2; ++n)
        acc[m][n] = MFMA16(af[m], bfv[n], acc[m][n]);
    __syncthreads();
  }

#pragma unroll
  for (int n = 0; n < 2; ++n) {
    const int col = nbase + wc * 32 + n * 16 + l15;
    const float bv_ = bias[col];
#pragma unroll
    for (int m = 0; m < 4; ++m)
#pragma unroll
      for (int j = 0; j < 4; ++j) {
        const int row = mbase + wr * 64 + m * 16 + lhi * 4 + j;
        outp[(size_t)row * D_ + col] = acc[m][n][j] + bv_;
      }
  }
}

// ---------------- flash attention (causal): 8-wave blocks, KV=128 per round ----------------
// Block = 8 waves (512 thr). Intra-block causal pairing: waves 0-3 own q-tile p,
// waves 4-7 own q-tile 31-p (64-row tiles) -> uniform live work per SIMD under any
// block->CU mapping. Each round stages a 128-wide K/V slab (two 64-kv sub-tiles).
// Staging addresses HOISTED; softmax exp2 via raw v_exp_f32; defer-max (T13, THR=8).
// SWAPPED S^T = mfma(K,Q); P A-fragments built in registers (cvt_pk + shfl_xor(16)),
// kv-chunk permutation pi(lhi)=bitswap applied to P and V fragments.
// K LDS [128 rows][8 chunks] slot c^(r&7); V LDS [64 rows][16 chunks] slot c^(r&15).
__global__ __launch_bounds__(512, 4) void attn_kernel(const bf16* __restrict__ Q,
                                                      const bf16* __restrict__ Kg,
                                                      const bf16* __restrict__ Vt,
                                                      bf16* __restrict__ Mg) {
  __shared__ __align__(16) bf16 Kl[2][128 * 64];
  __shared__ __align__(16) bf16 Vl[2][64 * 128];
  const int tid = threadIdx.x, lane = tid & 63, wid = tid >> 6;
  const int l15 = lane & 15, lhi = lane >> 4;
  const int p  = blockIdx.x & 15;             // complementary q-tile pair index
  const int bh = blockIdx.x >> 4;             // adjacent bids share bh -> K/V L2 locality
  const int half = wid >> 2, w4 = wid & 3;
  const int qtile = half ? (31 - p) : p;
  const int qbase = qtile * 64 + w4 * 16;
  const int b = bh >> 4, h = bh & 15;

  const bf16* Qp = Q  + (size_t)bh * T_ * DK_;
  const bf16* Kp = Kg + (size_t)bh * T_ * DK_;
  const bf16* Vp = Vt + (size_t)bh * DK_ * T_;

  const bf16x8 qf0 = *reinterpret_cast<const bf16x8*>(&Qp[(size_t)(qbase + l15) * DK_ + lhi * 8]);
  const bf16x8 qf1 = *reinterpret_cast<const bf16x8*>(&Qp[(size_t)(qbase + l15) * DK_ + 32 + lhi * 8]);

  bf16x8 onesb;
#pragma unroll
  for (int i = 0; i < 8; ++i) onesb[i] = (__bf16)1.0f;

  f32x4 o[4] = {};
  f32x4 lacc = {};
  float mrow = -1e30f;  // running max for this lane's q-row (q = qbase + l15)

  const int ntr = (33 - p) >> 1;  // 128-wide rounds covering high tile's causal extent

  // hoisted per-thread staging sources (T2 pre-swizzle folded in once)
  const int iA = tid, iB = 512 + tid;
  const bf16* ks0 = Kp + (size_t)(iA >> 3) * DK_ + (((iA & 7) ^ ((iA >> 3) & 7)) * 8);
  const bf16* ks1 = Kp + (size_t)(iB >> 3) * DK_ + (((iB & 7) ^ ((iB >> 3) & 7)) * 8);
  const bf16* vs0 = Vp + (size_t)(iA >> 4) * T_ + (((iA & 15) ^ ((iA >> 4) & 15)) * 8);
  const bf16* vs1 = Vp + (size_t)(iB >> 4) * T_ + (((iB & 15) ^ ((iB >> 4) & 15)) * 8);
  const int ub0 = wid * 1024;           // wave-uniform LDS byte base, it=0
  const int ub1 = 8192 + wid * 1024;    // it=1

  // stage round 0 into buffer 0
  gld_lds16(ks0, (char*)Kl[0] + ub0);
  gld_lds16(ks1, (char*)Kl[0] + ub1);
  gld_lds16(vs0, (char*)Vl[0] + ub0);
  gld_lds16(vs1, (char*)Vl[0] + ub1);
  ks0 += 128 * DK_; ks1 += 128 * DK_; vs0 += 128; vs1 += 128;
  __syncthreads();

  for (int rnd = 0; rnd < ntr; ++rnd) {
    const int cur = rnd & 1;
    const char* Kb_ = cur ? (const char*)Kl[1] : (const char*)Kl[0];
    const char* Vb_ = cur ? (const char*)Vl[1] : (const char*)Vl[0];
    if (rnd + 1 < ntr) {  // stage next slab into the other buffer
      char* Kn = cur ? (char*)Kl[0] : (char*)Kl[1];
      char* Vn = cur ? (char*)Vl[0] : (char*)Vl[1];
      gld_lds16(ks0, Kn + ub0);
      gld_lds16(ks1, Kn + ub1);
      gld_lds16(vs0, Vn + ub0);
      gld_lds16(vs1, Vn + ub1);
      ks0 += 128 * DK_; ks1 += 128 * DK_; vs0 += 128; vs1 += 128;
    }

#pragma unroll
    for (int sub = 0; sub < 2; ++sub) {
      const int kv0 = rnd * 128 + sub * 64;
      if (kv0 <= qbase + 15) {  // wave-uniform: wave has live columns in this sub-tile
        // ---- S^T = K Q^T : lane holds q=l15; rows kv = kv0 + s*16 + lhi*4 + j
        f32x4 sv[4];
#pragma unroll
        for (int s = 0; s < 4; ++s) {
          const int cbase = kv0 + s * 16;
          if (cbase <= qbase + 15) {
            const int row = sub * 64 + s * 16 + l15;  // row & 7 == l15 & 7
            const int rsw = l15 & 7;
            const bf16x8 k0 = *reinterpret_cast<const bf16x8*>(Kb_ + row * 128 + ((lhi       ^ rsw) * 16));
            const bf16x8 k1 = *reinterpret_cast<const bf16x8*>(Kb_ + row * 128 + (((4 + lhi) ^ rsw) * 16));
            f32x4 z = {};
            z = MFMA16(k0, qf0, z);          // swapped operand order
            sv[s] = MFMA16(k1, qf1, z);
          } else {
#pragma unroll
            for (int j = 0; j < 4; ++j) sv[s][j] = -1e30f;
          }
        }

        // ---- causal mask (kv = row, q = col): only the diagonal-straddling s-tile
#pragma unroll
        for (int s = 0; s < 4; ++s) {
          const int cbase = kv0 + s * 16;
          if (cbase <= qbase + 15 && cbase + 15 > qbase) {
            const int r = qbase + l15;
#pragma unroll
            for (int j = 0; j < 4; ++j) {
              const int c = cbase + lhi * 4 + j;
              sv[s][j] = (c <= r) ? sv[s][j] : -1e30f;
            }
          }
        }

        // ---- online softmax (exp2 domain), defer-max (T13): in-lane max only
        float ml = sv[0][0];
#pragma unroll
        for (int s = 0; s < 4; ++s)
#pragma unroll
          for (int j = 0; j < 4; ++j) ml = fmaxf(ml, sv[s][j]);

        if (__any(ml > mrow + 8.0f)) {
          float mx = ml;
          mx = fmaxf(mx, __shfl_xor(mx, 16, 64));
          mx = fmaxf(mx, __shfl_xor(mx, 32, 64));
          const float mn = fmaxf(mrow, mx);
          const float sc = FEXP2(mrow - mn);
          mrow = mn;
          // broadcast sc into O-layout rows: row q' = lhi*4 + j lives in lane q'
          const int sci = __float_as_int(sc);
#pragma unroll
          for (int j = 0; j < 4; ++j) {
            const float scj = __int_as_float(
                __builtin_amdgcn_ds_bpermute((lhi * 4 + j) * 4, sci));
            lacc[j] *= scj;
            o[0][j] *= scj; o[1][j] *= scj; o[2][j] *= scj; o[3][j] *= scj;
          }
        }
#pragma unroll
        for (int s = 0; s < 4; ++s)
#pragma unroll
          for (int j = 0; j < 4; ++j) sv[s][j] = FEXP2(sv[s][j] - mrow);

        // ---- P A-fragments in registers (no LDS round-trip).
        // Lane's k-slot chunk holds kv chunk pi(lhi), pi = [0,2,1,3] (bitswap).
        const bool oddl = (lhi & 1) != 0;
        bf16x8 pf[2];
#pragma unroll
        for (int hh = 0; hh < 2; ++hh) {
          const uint32_t u0l = cvtpk_bf16(sv[2 * hh][0], sv[2 * hh][1]);
          const uint32_t u0h = cvtpk_bf16(sv[2 * hh][2], sv[2 * hh][3]);
          const uint32_t u1l = cvtpk_bf16(sv[2 * hh + 1][0], sv[2 * hh + 1][1]);
          const uint32_t u1h = cvtpk_bf16(sv[2 * hh + 1][2], sv[2 * hh + 1][3]);
          const uint32_t sl = oddl ? u0l : u1l;
          const uint32_t sh = oddl ? u0h : u1h;
          const uint32_t rl = (uint32_t)__shfl_xor((int)sl, 16, 64);
          const uint32_t rh = (uint32_t)__shfl_xor((int)sh, 16, 64);
          union { uint32_t w[4]; bf16x8 v; } fr;
          fr.w[0] = oddl ? rl : u0l;
          fr.w[1] = oddl ? rh : u0h;
          fr.w[2] = oddl ? u1l : rl;
          fr.w[3] = oddl ? u1h : rh;
          pf[hh] = fr.v;
        }

        // ---- V fragments from LDS with the same kv-chunk permutation pi(lhi)
        const int pl = ((lhi & 1) << 1) | (lhi >> 1);
        bf16x8 vf[8];
#pragma unroll
        for (int d = 0; d < 4; ++d) {
          const int rowv = d * 16 + l15;  // rowv & 15 == l15
#pragma unroll
          for (int s2 = 0; s2 < 2; ++s2) {
            const int cread = sub * 8 + s2 * 4 + pl;
            vf[d * 2 + s2] = *reinterpret_cast<const bf16x8*>(
                Vb_ + rowv * 256 + ((cread ^ l15) * 16));
          }
        }

        // ---- O += P V ; row-sums l += P 1 (same C layout & rescale as O)
#pragma unroll
        for (int d = 0; d < 4; ++d) {
          o[d] = MFMA16(pf[0], vf[d * 2 + 0], o[d]);
          o[d] = MFMA16(pf[1], vf[d * 2 + 1], o[d]);
        }
        lacc = MFMA16(pf[0], onesb, lacc);
        lacc = MFMA16(pf[1], onesb, lacc);
      }
    }

    __syncthreads();  // drains vmcnt (next slab staged) + orders buffer reuse
  }

#pragma unroll
  for (int j = 0; j < 4; ++j) {
    const float inv = 1.0f / lacc[j];
    const int tq = qbase + lhi * 4 + j;
#pragma unroll
    for (int d = 0; d < 4; ++d)
      Mg[((size_t)b * T_ + tq) * D_ + h * DK_ + d * 16 + l15] = __float2bfloat16(o[d][j] * inv);
  }
}

// ---------------- launch ----------------
extern "C" void kernel_launch(void* const* d_in, const int* in_sizes, int n_in,
                              void* d_out, int out_size, void* d_ws, size_t ws_size,
                              hipStream_t stream) {
  (void)in_sizes; (void)n_in; (void)out_size; (void)ws_size;
  const float* x  = (const float*)d_in[0];
  const float* Wq = (const float*)d_in[1];
  const float* bq = (const float*)d_in[2];
  const float* Wk = (const float*)d_in[3];
  const float* bk = (const float*)d_in[4];
  const float* Wv = (const float*)d_in[5];
  const float* bv = (const float*)d_in[6];
  const float* Wo = (const float*)d_in[7];
  const float* bo = (const float*)d_in[8];
  float* out = (float*)d_out;

  // workspace layout (40 MB): Mg aliases xb (xb dead after QKV GEMM, attn runs after)
  char* ws = (char*)d_ws;
  bf16* xb  = (bf16*)(ws);                       // 8 MB [4096][1024]
  bf16* Mg  = (bf16*)(ws);                       // 8 MB [4096][1024] (alias, written by attn)
  bf16* Wt  = (bf16*)(ws + (size_t)( 8u << 20)); // 6 MB [3072][1024] (Wq|Wk|Wv transposed)
  bf16* Wot = (bf16*)(ws + (size_t)(14u << 20)); // 2 MB [1024][1024] (Wo transposed)
  bf16* Qb  = (bf16*)(ws + (size_t)(16u << 20)); // 8 MB [32][2048][64]
  bf16* Kb  = (bf16*)(ws + (size_t)(24u << 20)); // 8 MB [32][2048][64]
  bf16* Vt  = (bf16*)(ws + (size_t)(32u << 20)); // 8 MB [32][64][2048]

  pack_all_kernel<<<5120, 256, 0, stream>>>(x, Wq, Wk, Wv, Wo, xb, Wt, Wot);
  // fused QKV: C[4096][3072] = xb @ [Wq|Wk|Wv]
  gemm_qkv_kernel<<<dim3(24, 32), 256, 0, stream>>>(xb, Wt, bq, bk, bv, Qb, Kb, Vt);
  attn_kernel<<<dim3(512), 512, 0, stream>>>(Qb, Kb, Vt, Mg);
  // out[4096][1024] = Mg @ Wo + bo
  gemm_out_kernel<<<dim3(16, 32), 256, 0, stream>>>(Mg, Wot, bo, out);
}

// Round 14
// 104.473 us; speedup vs baseline: 1.1305x; 1.0338x over previous
//
#include <hip/hip_runtime.h>
#include <hip/hip_bf16.h>
#include <cstdint>
#include <cstddef>

// MHA forward: B=2, T=2048, D=1024, H=16, dk=64. fp32 in/out, bf16 MFMA internal.
#define B_  2
#define T_  2048
#define D_  1024
#define H_  16
#define DK_ 64

typedef __hip_bfloat16 bf16;
typedef __bf16 bf16x8 __attribute__((ext_vector_type(8)));  // MFMA A/B frag (4 VGPRs)
typedef float  f32x4  __attribute__((ext_vector_type(4)));  // MFMA C/D frag

#define MFMA16(a, b, c) __builtin_amdgcn_mfma_f32_16x16x32_bf16((a), (b), (c), 0, 0, 0)

// Q production scale: 1/sqrt(64) * log2(e)  (softmax done in exp2 domain)
#define SCALE_Q 0.1803368801111137f

// fast exp2: raw v_exp_f32 (no denorm fixup; inputs are either ~[-30,8] or -inf-ish)
#if defined(__has_builtin)
#if __has_builtin(__builtin_amdgcn_exp2f)
#define FEXP2(x) __builtin_amdgcn_exp2f(x)
#endif
#endif
#ifndef FEXP2
__device__ static inline float fexp2_asm(float x) {
  float r; asm("v_exp_f32 %0, %1" : "=v"(r) : "v"(x)); return r;
}
#define FEXP2(x) fexp2_asm(x)
#endif

__device__ static inline void gld_lds16(const void* g, void* l) {
  // async global->LDS, 16B per lane; LDS dest is wave-uniform base + lane*16
  __builtin_amdgcn_global_load_lds((const __attribute__((address_space(1))) void*)g,
                                   (__attribute__((address_space(3))) void*)l, 16, 0, 0);
}

__device__ static inline ushort f2bu(float x) {
  union { bf16 h; ushort u; } c;
  c.h = __float2bfloat16(x);
  return c.u;
}

__device__ static inline uint32_t cvtpk_bf16(float lo, float hi) {
  uint32_t r;
  asm volatile("v_cvt_pk_bf16_f32 %0, %1, %2" : "=v"(r) : "v"(lo), "v"(hi));
  return r;  // low16 = bf16(lo), high16 = bf16(hi)
}

// ---------------- fused pack: x fp32->bf16 (bids 0..4095) + W transpose (bids 4096..5119) ----------------
__global__ __launch_bounds__(256) void pack_all_kernel(const float* __restrict__ x,
                                                       const float* __restrict__ Wq,
                                                       const float* __restrict__ Wk,
                                                       const float* __restrict__ Wv,
                                                       const float* __restrict__ Wo,
                                                       bf16* __restrict__ xb,
                                                       bf16* __restrict__ Wt,    // [3072][1024]
                                                       bf16* __restrict__ Wot) { // [1024][1024]
  __shared__ bf16 t[64][65];  // +1 pad breaks bank conflicts on transposed read
  const int bid = blockIdx.x;
  const int tid = threadIdx.x;
  if (bid < 4096) {
    // ---- pack x: 4 fp32 -> 4 bf16 per thread
    const int i = bid * 256 + tid;
    const float4 v = reinterpret_cast<const float4*>(x)[i];
    union { ushort4 u; bf16 h[4]; } c;
    c.h[0] = __float2bfloat16(v.x);
    c.h[1] = __float2bfloat16(v.y);
    c.h[2] = __float2bfloat16(v.z);
    c.h[3] = __float2bfloat16(v.w);
    reinterpret_cast<ushort4*>(xb)[i] = c.u;
    return;
  }
  // ---- pack W: transpose+convert 64x64 tiles
  const int wb  = bid - 4096;
  const int mat  = wb >> 8;        // 0..3 : Wq,Wk,Wv,Wo
  const int tile = wb & 255;       // 16x16 tiles of 64x64
  const int tr = tile >> 4, tc = tile & 15;
  const float* W = (mat == 0) ? Wq : (mat == 1) ? Wk : (mat == 2) ? Wv : Wo;
#pragma unroll
  for (int i = 0; i < 16; ++i) {
    const int idx = i * 256 + tid;
    const int r = idx >> 6, c = idx & 63;
    t[r][c] = __float2bfloat16(W[(size_t)(tr * 64 + r) * D_ + tc * 64 + c]);
  }
  __syncthreads();
  bf16* dst = (mat == 3) ? Wot : (Wt + (size_t)mat * D_ * D_);
#pragma unroll
  for (int i = 0; i < 16; ++i) {
    const int idx = i * 256 + tid;
    const int n = idx >> 6, k = idx & 63;
    dst[(size_t)(tc * 64 + n) * D_ + tr * 64 + k] = t[k][n];
  }
}

// ---------------- QKV GEMM: 128x128 bf16, BK=32, 4 waves (2x2 of 64x64) ----------------
// A: [M][K] row-major bf16.  Bt: [N][K] row-major bf16 (i.e. B transposed).
// Epilogue -> Qb/Kb [BH][T][64], Vt [BH][64][T] (V packed 4t/store), + bias;
// Q scaled by SCALE_Q.
__global__ __launch_bounds__(256, 3) void gemm_qkv_kernel(
    const bf16* __restrict__ A, const bf16* __restrict__ Bt,
    const float* __restrict__ bias0, const float* __restrict__ bias1,
    const float* __restrict__ bias2,
    bf16* __restrict__ Qb, bf16* __restrict__ Kb, bf16* __restrict__ Vt) {
  __shared__ bf16 As[128 * 32];
  __shared__ bf16 Bs[128 * 32];
  const int tid  = threadIdx.x;
  const int lane = tid & 63, wid = tid >> 6;
  const int wr = wid >> 1, wc = wid & 1;
  const int l15 = lane & 15, lhi = lane >> 4;
  const int mbase = blockIdx.y * 128, nbase = blockIdx.x * 128;

  f32x4 acc[4][4] = {};

  const int r0  = tid >> 2;        // staged row for chunk p=0 (p=1 is +64)
  const int kc0 = (tid & 3) * 8;   // k offset within BK
  char* AsB = (char*)As;
  char* BsB = (char*)Bs;

  for (int kt = 0; kt < D_; kt += 32) {
    gld_lds16(A  + (size_t)(mbase + r0)      * D_ + kt + kc0, AsB + wid * 1024);
    gld_lds16(A  + (size_t)(mbase + 64 + r0) * D_ + kt + kc0, AsB + 4096 + wid * 1024);
    gld_lds16(Bt + (size_t)(nbase + r0)      * D_ + kt + kc0, BsB + wid * 1024);
    gld_lds16(Bt + (size_t)(nbase + 64 + r0) * D_ + kt + kc0, BsB + 4096 + wid * 1024);
    __syncthreads();  // compiler drains vmcnt before barrier

    bf16x8 af[4], bfv[4];
#pragma unroll
    for (int m = 0; m < 4; ++m)
      af[m] = *reinterpret_cast<const bf16x8*>(&As[(wr * 64 + m * 16 + l15) * 32 + lhi * 8]);
#pragma unroll
    for (int n = 0; n < 4; ++n)
      bfv[n] = *reinterpret_cast<const bf16x8*>(&Bs[(wc * 64 + n * 16 + l15) * 32 + lhi * 8]);
#pragma unroll
    for (int m = 0; m < 4; ++m)
#pragma unroll
      for (int n = 0; n < 4; ++n)
        acc[m][n] = MFMA16(af[m], bfv[n], acc[m][n]);
    __syncthreads();
  }

  // epilogue: D layout col = lane&15, row = (lane>>4)*4 + j
#pragma unroll
  for (int n = 0; n < 4; ++n) {
    const int col = nbase + wc * 64 + n * 16 + l15;
    const int seg  = col >> 10;      // 0=Q 1=K 2=V (uniform per block)
    const int ncol = col & 1023;
    const float* bias = (seg == 0) ? bias0 : (seg == 1) ? bias1 : bias2;
    const float bv_ = bias[ncol];
    const int h = ncol >> 6, dk = ncol & 63;
    if (seg == 2) {
      // V: pack 4 consecutive t (j=0..3) into one 8B store
#pragma unroll
      for (int m = 0; m < 4; ++m) {
        const int t0 = mbase + wr * 64 + m * 16 + lhi * 4;  // multiple of 4
        const int b = t0 >> 11, t = t0 & 2047;
        union { ushort u[4]; uint2 v; } pk;
#pragma unroll
        for (int j = 0; j < 4; ++j) pk.u[j] = f2bu(acc[m][n][j] + bv_);
        *reinterpret_cast<uint2*>(&Vt[((size_t)(b * H_ + h) * DK_ + dk) * T_ + t]) = pk.v;
      }
    } else {
#pragma unroll
      for (int m = 0; m < 4; ++m) {
#pragma unroll
        for (int j = 0; j < 4; ++j) {
          const int row = mbase + wr * 64 + m * 16 + lhi * 4 + j;
          const int b = row >> 11, t = row & 2047;
          const int bh = b * H_ + h;
          float outv = acc[m][n][j] + bv_;
          if (seg == 0) outv *= SCALE_Q;  // fold 1/sqrt(dk)*log2(e) into Q
          const bf16 hv = __float2bfloat16(outv);
          if (seg == 0) Qb[((size_t)bh * T_ + t) * DK_ + dk] = hv;
          else          Kb[((size_t)bh * T_ + t) * DK_ + dk] = hv;
        }
      }
    }
  }
}

// ---------------- out GEMM: 128x64 tile, BK=64, 4 waves (2x2 of 64x32) ----------------
// out[4096][1024] = A @ Wot^T + bias ; grid (16, 32) = 512 blocks -> 2 blocks/CU.
// BK=64 halves barrier count vs BK=32 (16 rounds x 16 MFMA). LDS rows of 8x16B
// chunks, slot c^(r&7) (T2 swizzle via pre-swizzled source; reads XOR l15&7 --
// same addressing as the verified R11 phase macro).
__global__ __launch_bounds__(256, 2) void gemm_out_kernel(
    const bf16* __restrict__ A, const bf16* __restrict__ Bt,
    const float* __restrict__ bias, float* __restrict__ outp) {
  __shared__ __align__(16) bf16 As[128 * 64];  // 16 KB
  __shared__ __align__(16) bf16 Bs[64 * 64];   //  8 KB
  const int tid  = threadIdx.x;
  const int lane = tid & 63, wid = tid >> 6;
  const int wr = wid >> 1, wc = wid & 1;
  const int l15 = lane & 15, lhi = lane >> 4;
  const int mbase = blockIdx.y * 128, nbase = blockIdx.x * 64;

  f32x4 acc[4][2] = {};

  // hoisted staging sources: chunk idx = it*256 + tid; r = idx>>3, c = idx&7,
  // src col = (c ^ (r&7))*8; LDS dest byte = idx*16 (= wave-uniform + lane*16).
  const bf16* sa0; const bf16* sa1; const bf16* sa2; const bf16* sa3;
  const bf16* sb0; const bf16* sb1;
  {
    const int iA0 = tid, iA1 = 256 + tid, iA2 = 512 + tid, iA3 = 768 + tid;
    sa0 = A + (size_t)(mbase + (iA0 >> 3)) * D_ + (((iA0 & 7) ^ ((iA0 >> 3) & 7)) * 8);
    sa1 = A + (size_t)(mbase + (iA1 >> 3)) * D_ + (((iA1 & 7) ^ ((iA1 >> 3) & 7)) * 8);
    sa2 = A + (size_t)(mbase + (iA2 >> 3)) * D_ + (((iA2 & 7) ^ ((iA2 >> 3) & 7)) * 8);
    sa3 = A + (size_t)(mbase + (iA3 >> 3)) * D_ + (((iA3 & 7) ^ ((iA3 >> 3) & 7)) * 8);
    sb0 = Bt + (size_t)(nbase + (iA0 >> 3)) * D_ + (((iA0 & 7) ^ ((iA0 >> 3) & 7)) * 8);
    sb1 = Bt + (size_t)(nbase + (iA1 >> 3)) * D_ + (((iA1 & 7) ^ ((iA1 >> 3) & 7)) * 8);
  }
  const int ub = wid * 1024;  // wave-uniform LDS byte base per 256-chunk group

  for (int kt = 0; kt < D_; kt += 64) {
    gld_lds16(sa0 + kt, (char*)As + ub);
    gld_lds16(sa1 + kt, (char*)As + 4096 + ub);
    gld_lds16(sa2 + kt, (char*)As + 8192 + ub);
    gld_lds16(sa3 + kt, (char*)As + 12288 + ub);
    gld_lds16(sb0 + kt, (char*)Bs + ub);
    gld_lds16(sb1 + kt, (char*)Bs + 4096 + ub);
    __syncthreads();  // compiler drains vmcnt before barrier

    const int rsw = l15 & 7;
    bf16x8 af[4][2], bfv[2][2];
#pragma unroll
    for (int m = 0; m < 4; ++m)
#pragma unroll
      for (int kk = 0; kk < 2; ++kk)
        af[m][kk] = *reinterpret_cast<const bf16x8*>(
            (const char*)As + (wr * 64 + m * 16 + l15) * 128 + (((kk * 4 + lhi) ^ rsw) * 16));
#pragma unroll
    for (int n = 0; n < 2; ++n)
#pragma unroll
      for (int kk = 0; kk < 2; ++kk)
        bfv[n][kk] = *reinterpret_cast<const bf16x8*>(
            (const char*)Bs + (wc * 32 + n * 16 + l15) * 128 + (((kk * 4 + lhi) ^ rsw) * 16));
#pragma unroll
    for (int m = 0; m < 4; ++m)
#pragma unroll
      for (int n = 0; n < 2; ++n)
#pragma unroll
        for (int kk = 0; kk < 2; ++kk)
          acc[m][n] = MFMA16(af[m][kk], bfv[n][kk], acc[m][n]);
    __syncthreads();
  }

#pragma unroll
  for (int n = 0; n < 2; ++n) {
    const int col = nbase + wc * 32 + n * 16 + l15;
    const float bv_ = bias[col];
#pragma unroll
    for (int m = 0; m < 4; ++m)
#pragma unroll
      for (int j = 0; j < 4; ++j) {
        const int row = mbase + wr * 64 + m * 16 + lhi * 4 + j;
        outp[(size_t)row * D_ + col] = acc[m][n][j] + bv_;
      }
  }
}

// ---------------- flash attention (causal): 8-wave blocks, KV=128 per round ----------------
// Block = 8 waves (512 thr). Intra-block causal pairing: waves 0-3 own q-tile p,
// waves 4-7 own q-tile 31-p (64-row tiles) -> uniform live work per SIMD under any
// block->CU mapping. Each round stages a 128-wide K/V slab (two 64-kv sub-tiles).
// Staging addresses HOISTED; softmax exp2 via raw v_exp_f32; defer-max (T13, THR=8).
// SWAPPED S^T = mfma(K,Q); P A-fragments built in registers (cvt_pk + shfl_xor(16)),
// kv-chunk permutation pi(lhi)=bitswap applied to P and V fragments.
// K LDS [128 rows][8 chunks] slot c^(r&7); V LDS [64 rows][16 chunks] slot c^(r&15).
// T5: setprio(1) around the QK^T and PV MFMA clusters (attn-proven, m191).
__global__ __launch_bounds__(512, 4) void attn_kernel(const bf16* __restrict__ Q,
                                                      const bf16* __restrict__ Kg,
                                                      const bf16* __restrict__ Vt,
                                                      bf16* __restrict__ Mg) {
  __shared__ __align__(16) bf16 Kl[2][128 * 64];
  __shared__ __align__(16) bf16 Vl[2][64 * 128];
  const int tid = threadIdx.x, lane = tid & 63, wid = tid >> 6;
  const int l15 = lane & 15, lhi = lane >> 4;
  const int p  = blockIdx.x & 15;             // complementary q-tile pair index
  const int bh = blockIdx.x >> 4;             // adjacent bids share bh -> K/V L2 locality
  const int half = wid >> 2, w4 = wid & 3;
  const int qtile = half ? (31 - p) : p;
  const int qbase = qtile * 64 + w4 * 16;
  const int b = bh >> 4, h = bh & 15;

  const bf16* Qp = Q  + (size_t)bh * T_ * DK_;
  const bf16* Kp = Kg + (size_t)bh * T_ * DK_;
  const bf16* Vp = Vt + (size_t)bh * DK_ * T_;

  const bf16x8 qf0 = *reinterpret_cast<const bf16x8*>(&Qp[(size_t)(qbase + l15) * DK_ + lhi * 8]);
  const bf16x8 qf1 = *reinterpret_cast<const bf16x8*>(&Qp[(size_t)(qbase + l15) * DK_ + 32 + lhi * 8]);

  bf16x8 onesb;
#pragma unroll
  for (int i = 0; i < 8; ++i) onesb[i] = (__bf16)1.0f;

  f32x4 o[4] = {};
  f32x4 lacc = {};
  float mrow = -1e30f;  // running max for this lane's q-row (q = qbase + l15)

  const int ntr = (33 - p) >> 1;  // 128-wide rounds covering high tile's causal extent

  // hoisted per-thread staging sources (T2 pre-swizzle folded in once)
  const int iA = tid, iB = 512 + tid;
  const bf16* ks0 = Kp + (size_t)(iA >> 3) * DK_ + (((iA & 7) ^ ((iA >> 3) & 7)) * 8);
  const bf16* ks1 = Kp + (size_t)(iB >> 3) * DK_ + (((iB & 7) ^ ((iB >> 3) & 7)) * 8);
  const bf16* vs0 = Vp + (size_t)(iA >> 4) * T_ + (((iA & 15) ^ ((iA >> 4) & 15)) * 8);
  const bf16* vs1 = Vp + (size_t)(iB >> 4) * T_ + (((iB & 15) ^ ((iB >> 4) & 15)) * 8);
  const int ub0 = wid * 1024;           // wave-uniform LDS byte base, it=0
  const int ub1 = 8192 + wid * 1024;    // it=1

  // stage round 0 into buffer 0
  gld_lds16(ks0, (char*)Kl[0] + ub0);
  gld_lds16(ks1, (char*)Kl[0] + ub1);
  gld_lds16(vs0, (char*)Vl[0] + ub0);
  gld_lds16(vs1, (char*)Vl[0] + ub1);
  ks0 += 128 * DK_; ks1 += 128 * DK_; vs0 += 128; vs1 += 128;
  __syncthreads();

  for (int rnd = 0; rnd < ntr; ++rnd) {
    const int cur = rnd & 1;
    const char* Kb_ = cur ? (const char*)Kl[1] : (const char*)Kl[0];
    const char* Vb_ = cur ? (const char*)Vl[1] : (const char*)Vl[0];
    if (rnd + 1 < ntr) {  // stage next slab into the other buffer
      char* Kn = cur ? (char*)Kl[0] : (char*)Kl[1];
      char* Vn = cur ? (char*)Vl[0] : (char*)Vl[1];
      gld_lds16(ks0, Kn + ub0);
      gld_lds16(ks1, Kn + ub1);
      gld_lds16(vs0, Vn + ub0);
      gld_lds16(vs1, Vn + ub1);
      ks0 += 128 * DK_; ks1 += 128 * DK_; vs0 += 128; vs1 += 128;
    }

#pragma unroll
    for (int sub = 0; sub < 2; ++sub) {
      const int kv0 = rnd * 128 + sub * 64;
      if (kv0 <= qbase + 15) {  // wave-uniform: wave has live columns in this sub-tile
        // ---- S^T = K Q^T : lane holds q=l15; rows kv = kv0 + s*16 + lhi*4 + j
        f32x4 sv[4];
        __builtin_amdgcn_s_setprio(1);
#pragma unroll
        for (int s = 0; s < 4; ++s) {
          const int cbase = kv0 + s * 16;
          if (cbase <= qbase + 15) {
            const int row = sub * 64 + s * 16 + l15;  // row & 7 == l15 & 7
            const int rsw = l15 & 7;
            const bf16x8 k0 = *reinterpret_cast<const bf16x8*>(Kb_ + row * 128 + ((lhi       ^ rsw) * 16));
            const bf16x8 k1 = *reinterpret_cast<const bf16x8*>(Kb_ + row * 128 + (((4 + lhi) ^ rsw) * 16));
            f32x4 z = {};
            z = MFMA16(k0, qf0, z);          // swapped operand order
            sv[s] = MFMA16(k1, qf1, z);
          } else {
#pragma unroll
            for (int j = 0; j < 4; ++j) sv[s][j] = -1e30f;
          }
        }
        __builtin_amdgcn_s_setprio(0);

        // ---- causal mask (kv = row, q = col): only the diagonal-straddling s-tile
#pragma unroll
        for (int s = 0; s < 4; ++s) {
          const int cbase = kv0 + s * 16;
          if (cbase <= qbase + 15 && cbase + 15 > qbase) {
            const int r = qbase + l15;
#pragma unroll
            for (int j = 0; j < 4; ++j) {
              const int c = cbase + lhi * 4 + j;
              sv[s][j] = (c <= r) ? sv[s][j] : -1e30f;
            }
          }
        }

        // ---- online softmax (exp2 domain), defer-max (T13): in-lane max only
        float ml = sv[0][0];
#pragma unroll
        for (int s = 0; s < 4; ++s)
#pragma unroll
          for (int j = 0; j < 4; ++j) ml = fmaxf(ml, sv[s][j]);

        if (__any(ml > mrow + 8.0f)) {
          float mx = ml;
          mx = fmaxf(mx, __shfl_xor(mx, 16, 64));
          mx = fmaxf(mx, __shfl_xor(mx, 32, 64));
          const float mn = fmaxf(mrow, mx);
          const float sc = FEXP2(mrow - mn);
          mrow = mn;
          // broadcast sc into O-layout rows: row q' = lhi*4 + j lives in lane q'
          const int sci = __float_as_int(sc);
#pragma unroll
          for (int j = 0; j < 4; ++j) {
            const float scj = __int_as_float(
                __builtin_amdgcn_ds_bpermute((lhi * 4 + j) * 4, sci));
            lacc[j] *= scj;
            o[0][j] *= scj; o[1][j] *= scj; o[2][j] *= scj; o[3][j] *= scj;
          }
        }
#pragma unroll
        for (int s = 0; s < 4; ++s)
#pragma unroll
          for (int j = 0; j < 4; ++j) sv[s][j] = FEXP2(sv[s][j] - mrow);

        // ---- P A-fragments in registers (no LDS round-trip).
        // Lane's k-slot chunk holds kv chunk pi(lhi), pi = [0,2,1,3] (bitswap).
        const bool oddl = (lhi & 1) != 0;
        bf16x8 pf[2];
#pragma unroll
        for (int hh = 0; hh < 2; ++hh) {
          const uint32_t u0l = cvtpk_bf16(sv[2 * hh][0], sv[2 * hh][1]);
          const uint32_t u0h = cvtpk_bf16(sv[2 * hh][2], sv[2 * hh][3]);
          const uint32_t u1l = cvtpk_bf16(sv[2 * hh + 1][0], sv[2 * hh + 1][1]);
          const uint32_t u1h = cvtpk_bf16(sv[2 * hh + 1][2], sv[2 * hh + 1][3]);
          const uint32_t sl = oddl ? u0l : u1l;
          const uint32_t sh = oddl ? u0h : u1h;
          const uint32_t rl = (uint32_t)__shfl_xor((int)sl, 16, 64);
          const uint32_t rh = (uint32_t)__shfl_xor((int)sh, 16, 64);
          union { uint32_t w[4]; bf16x8 v; } fr;
          fr.w[0] = oddl ? rl : u0l;
          fr.w[1] = oddl ? rh : u0h;
          fr.w[2] = oddl ? u1l : rl;
          fr.w[3] = oddl ? u1h : rh;
          pf[hh] = fr.v;
        }

        // ---- V fragments from LDS with the same kv-chunk permutation pi(lhi)
        const int pl = ((lhi & 1) << 1) | (lhi >> 1);
        bf16x8 vf[8];
#pragma unroll
        for (int d = 0; d < 4; ++d) {
          const int rowv = d * 16 + l15;  // rowv & 15 == l15
#pragma unroll
          for (int s2 = 0; s2 < 2; ++s2) {
            const int cread = sub * 8 + s2 * 4 + pl;
            vf[d * 2 + s2] = *reinterpret_cast<const bf16x8*>(
                Vb_ + rowv * 256 + ((cread ^ l15) * 16));
          }
        }

        // ---- O += P V ; row-sums l += P 1 (same C layout & rescale as O)
        __builtin_amdgcn_s_setprio(1);
#pragma unroll
        for (int d = 0; d < 4; ++d) {
          o[d] = MFMA16(pf[0], vf[d * 2 + 0], o[d]);
          o[d] = MFMA16(pf[1], vf[d * 2 + 1], o[d]);
        }
        lacc = MFMA16(pf[0], onesb, lacc);
        lacc = MFMA16(pf[1], onesb, lacc);
        __builtin_amdgcn_s_setprio(0);
      }
    }

    __syncthreads();  // drains vmcnt (next slab staged) + orders buffer reuse
  }

#pragma unroll
  for (int j = 0; j < 4; ++j) {
    const float inv = 1.0f / lacc[j];
    const int tq = qbase + lhi * 4 + j;
#pragma unroll
    for (int d = 0; d < 4; ++d)
      Mg[((size_t)b * T_ + tq) * D_ + h * DK_ + d * 16 + l15] = __float2bfloat16(o[d][j] * inv);
  }
}

// ---------------- launch ----------------
extern "C" void kernel_launch(void* const* d_in, const int* in_sizes, int n_in,
                              void* d_out, int out_size, void* d_ws, size_t ws_size,
                              hipStream_t stream) {
  (void)in_sizes; (void)n_in; (void)out_size; (void)ws_size;
  const float* x  = (const float*)d_in[0];
  const float* Wq = (const float*)d_in[1];
  const float* bq = (const float*)d_in[2];
  const float* Wk = (const float*)d_in[3];
  const float* bk = (const float*)d_in[4];
  const float* Wv = (const float*)d_in[5];
  const float* bv = (const float*)d_in[6];
  const float* Wo = (const float*)d_in[7];
  const float* bo = (const float*)d_in[8];
  float* out = (float*)d_out;

  // workspace layout (40 MB): Mg aliases xb (xb dead after QKV GEMM, attn runs after)
  char* ws = (char*)d_ws;
  bf16* xb  = (bf16*)(ws);                       // 8 MB [4096][1024]
  bf16* Mg  = (bf16*)(ws);                       // 8 MB [4096][1024] (alias, written by attn)
  bf16* Wt  = (bf16*)(ws + (size_t)( 8u << 20)); // 6 MB [3072][1024] (Wq|Wk|Wv transposed)
  bf16* Wot = (bf16*)(ws + (size_t)(14u << 20)); // 2 MB [1024][1024] (Wo transposed)
  bf16* Qb  = (bf16*)(ws + (size_t)(16u << 20)); // 8 MB [32][2048][64]
  bf16* Kb  = (bf16*)(ws + (size_t)(24u << 20)); // 8 MB [32][2048][64]
  bf16* Vt  = (bf16*)(ws + (size_t)(32u << 20)); // 8 MB [32][64][2048]

  pack_all_kernel<<<5120, 256, 0, stream>>>(x, Wq, Wk, Wv, Wo, xb, Wt, Wot);
  // fused QKV: C[4096][3072] = xb @ [Wq|Wk|Wv]
  gemm_qkv_kernel<<<dim3(24, 32), 256, 0, stream>>>(xb, Wt, bq, bk, bv, Qb, Kb, Vt);
  attn_kernel<<<dim3(512), 512, 0, stream>>>(Qb, Kb, Vt, Mg);
  // out[4096][1024] = Mg @ Wo + bo
  gemm_out_kernel<<<dim3(16, 32), 256, 0, stream>>>(Mg, Wot, bo, out);
}

// Round 15
// 98.488 us; speedup vs baseline: 1.1992x; 1.0608x over previous
//
#include <hip/hip_runtime.h>
#include <hip/hip_bf16.h>
#include <cstdint>
#include <cstddef>

// MHA forward: B=2, T=2048, D=1024, H=16, dk=64. fp32 in/out, bf16 MFMA internal.
#define B_  2
#define T_  2048
#define D_  1024
#define H_  16
#define DK_ 64

typedef __hip_bfloat16 bf16;
typedef __bf16 bf16x8 __attribute__((ext_vector_type(8)));  // MFMA A/B frag (4 VGPRs)
typedef float  f32x4  __attribute__((ext_vector_type(4)));  // MFMA C/D frag

#define MFMA16(a, b, c) __builtin_amdgcn_mfma_f32_16x16x32_bf16((a), (b), (c), 0, 0, 0)

// Q production scale: 1/sqrt(64) * log2(e)  (softmax done in exp2 domain)
#define SCALE_Q 0.1803368801111137f

// fast exp2: raw v_exp_f32 (no denorm fixup; inputs are either ~[-30,8] or -inf-ish)
#if defined(__has_builtin)
#if __has_builtin(__builtin_amdgcn_exp2f)
#define FEXP2(x) __builtin_amdgcn_exp2f(x)
#endif
#endif
#ifndef FEXP2
__device__ static inline float fexp2_asm(float x) {
  float r; asm("v_exp_f32 %0, %1" : "=v"(r) : "v"(x)); return r;
}
#define FEXP2(x) fexp2_asm(x)
#endif

__device__ static inline void gld_lds16(const void* g, void* l) {
  // async global->LDS, 16B per lane; LDS dest is wave-uniform base + lane*16
  __builtin_amdgcn_global_load_lds((const __attribute__((address_space(1))) void*)g,
                                   (__attribute__((address_space(3))) void*)l, 16, 0, 0);
}

__device__ static inline ushort f2bu(float x) {
  union { bf16 h; ushort u; } c;
  c.h = __float2bfloat16(x);
  return c.u;
}

__device__ static inline uint32_t cvtpk_bf16(float lo, float hi) {
  uint32_t r;
  asm volatile("v_cvt_pk_bf16_f32 %0, %1, %2" : "=v"(r) : "v"(lo), "v"(hi));
  return r;  // low16 = bf16(lo), high16 = bf16(hi)
}

// ---------------- fused pack: x fp32->bf16 (bids 0..4095) + W transpose (bids 4096..5119) ----------------
__global__ __launch_bounds__(256) void pack_all_kernel(const float* __restrict__ x,
                                                       const float* __restrict__ Wq,
                                                       const float* __restrict__ Wk,
                                                       const float* __restrict__ Wv,
                                                       const float* __restrict__ Wo,
                                                       bf16* __restrict__ xb,
                                                       bf16* __restrict__ Wt,    // [3072][1024]
                                                       bf16* __restrict__ Wot) { // [1024][1024]
  __shared__ bf16 t[64][65];  // +1 pad breaks bank conflicts on transposed read
  const int bid = blockIdx.x;
  const int tid = threadIdx.x;
  if (bid < 4096) {
    // ---- pack x: 4 fp32 -> 4 bf16 per thread
    const int i = bid * 256 + tid;
    const float4 v = reinterpret_cast<const float4*>(x)[i];
    union { ushort4 u; bf16 h[4]; } c;
    c.h[0] = __float2bfloat16(v.x);
    c.h[1] = __float2bfloat16(v.y);
    c.h[2] = __float2bfloat16(v.z);
    c.h[3] = __float2bfloat16(v.w);
    reinterpret_cast<ushort4*>(xb)[i] = c.u;
    return;
  }
  // ---- pack W: transpose+convert 64x64 tiles
  const int wb  = bid - 4096;
  const int mat  = wb >> 8;        // 0..3 : Wq,Wk,Wv,Wo
  const int tile = wb & 255;       // 16x16 tiles of 64x64
  const int tr = tile >> 4, tc = tile & 15;
  const float* W = (mat == 0) ? Wq : (mat == 1) ? Wk : (mat == 2) ? Wv : Wo;
#pragma unroll
  for (int i = 0; i < 16; ++i) {
    const int idx = i * 256 + tid;
    const int r = idx >> 6, c = idx & 63;
    t[r][c] = __float2bfloat16(W[(size_t)(tr * 64 + r) * D_ + tc * 64 + c]);
  }
  __syncthreads();
  bf16* dst = (mat == 3) ? Wot : (Wt + (size_t)mat * D_ * D_);
#pragma unroll
  for (int i = 0; i < 16; ++i) {
    const int idx = i * 256 + tid;
    const int n = idx >> 6, k = idx & 63;
    dst[(size_t)(tc * 64 + n) * D_ + tr * 64 + k] = t[k][n];
  }
}

// ---------------- QKV GEMM: 128x128 bf16, BK=64, 4 waves (2x2 of 64x64) ----------------
// A: [M][K] row-major bf16.  Bt: [N][K] row-major bf16 (B transposed).
// BK=64 halves barrier count (16 rounds x 32 MFMA). LDS rows of 8x16B chunks,
// slot c^(r&7) (T2 swizzle via pre-swizzled source; reads XOR l15&7) --
// addressing verified in R11/R14.
// Epilogue -> Qb/Kb [BH][T][64], Vt [BH][64][T] (V packed 4t/store), + bias;
// Q scaled by SCALE_Q.
__global__ __launch_bounds__(256, 3) void gemm_qkv_kernel(
    const bf16* __restrict__ A, const bf16* __restrict__ Bt,
    const float* __restrict__ bias0, const float* __restrict__ bias1,
    const float* __restrict__ bias2,
    bf16* __restrict__ Qb, bf16* __restrict__ Kb, bf16* __restrict__ Vt) {
  __shared__ __align__(16) bf16 As[128 * 64];  // 16 KB
  __shared__ __align__(16) bf16 Bs[128 * 64];  // 16 KB
  const int tid  = threadIdx.x;
  const int lane = tid & 63, wid = tid >> 6;
  const int wr = wid >> 1, wc = wid & 1;
  const int l15 = lane & 15, lhi = lane >> 4;
  const int mbase = blockIdx.y * 128, nbase = blockIdx.x * 128;

  f32x4 acc[4][4] = {};

  // hoisted staging sources: chunk idx = it*256 + tid (it=0..3); r=idx>>3, c=idx&7,
  // src col = (c^(r&7))*8; LDS dest byte = idx*16.
  const bf16* sa[4]; const bf16* sb[4];
#pragma unroll
  for (int it = 0; it < 4; ++it) {
    const int idx = it * 256 + tid;
    const int r = idx >> 3, cs = ((idx & 7) ^ ((idx >> 3) & 7)) * 8;
    sa[it] = A  + (size_t)(mbase + r) * D_ + cs;
    sb[it] = Bt + (size_t)(nbase + r) * D_ + cs;
  }
  const int ub = wid * 1024;  // wave-uniform LDS byte base within each 256-chunk group

  for (int kt = 0; kt < D_; kt += 64) {
#pragma unroll
    for (int it = 0; it < 4; ++it) {
      gld_lds16(sa[it] + kt, (char*)As + it * 4096 + ub);
      gld_lds16(sb[it] + kt, (char*)Bs + it * 4096 + ub);
    }
    __syncthreads();  // compiler drains vmcnt before barrier

    const int rsw = l15 & 7;
    bf16x8 af[4][2], bfv[4][2];
#pragma unroll
    for (int m = 0; m < 4; ++m)
#pragma unroll
      for (int kk = 0; kk < 2; ++kk)
        af[m][kk] = *reinterpret_cast<const bf16x8*>(
            (const char*)As + (wr * 64 + m * 16 + l15) * 128 + (((kk * 4 + lhi) ^ rsw) * 16));
#pragma unroll
    for (int n = 0; n < 4; ++n)
#pragma unroll
      for (int kk = 0; kk < 2; ++kk)
        bfv[n][kk] = *reinterpret_cast<const bf16x8*>(
            (const char*)Bs + (wc * 64 + n * 16 + l15) * 128 + (((kk * 4 + lhi) ^ rsw) * 16));
#pragma unroll
    for (int m = 0; m < 4; ++m)
#pragma unroll
      for (int n = 0; n < 4; ++n)
#pragma unroll
        for (int kk = 0; kk < 2; ++kk)
          acc[m][n] = MFMA16(af[m][kk], bfv[n][kk], acc[m][n]);
    __syncthreads();
  }

  // epilogue: D layout col = lane&15, row = (lane>>4)*4 + j
#pragma unroll
  for (int n = 0; n < 4; ++n) {
    const int col = nbase + wc * 64 + n * 16 + l15;
    const int seg  = col >> 10;      // 0=Q 1=K 2=V (uniform per block)
    const int ncol = col & 1023;
    const float* bias = (seg == 0) ? bias0 : (seg == 1) ? bias1 : bias2;
    const float bv_ = bias[ncol];
    const int h = ncol >> 6, dk = ncol & 63;
    if (seg == 2) {
      // V: pack 4 consecutive t (j=0..3) into one 8B store
#pragma unroll
      for (int m = 0; m < 4; ++m) {
        const int t0 = mbase + wr * 64 + m * 16 + lhi * 4;  // multiple of 4
        const int b = t0 >> 11, t = t0 & 2047;
        union { ushort u[4]; uint2 v; } pk;
#pragma unroll
        for (int j = 0; j < 4; ++j) pk.u[j] = f2bu(acc[m][n][j] + bv_);
        *reinterpret_cast<uint2*>(&Vt[((size_t)(b * H_ + h) * DK_ + dk) * T_ + t]) = pk.v;
      }
    } else {
#pragma unroll
      for (int m = 0; m < 4; ++m) {
#pragma unroll
        for (int j = 0; j < 4; ++j) {
          const int row = mbase + wr * 64 + m * 16 + lhi * 4 + j;
          const int b = row >> 11, t = row & 2047;
          const int bh = b * H_ + h;
          float outv = acc[m][n][j] + bv_;
          if (seg == 0) outv *= SCALE_Q;  // fold 1/sqrt(dk)*log2(e) into Q
          const bf16 hv = __float2bfloat16(outv);
          if (seg == 0) Qb[((size_t)bh * T_ + t) * DK_ + dk] = hv;
          else          Kb[((size_t)bh * T_ + t) * DK_ + dk] = hv;
        }
      }
    }
  }
}

// ---------------- out GEMM: 128x64 tile, BK=64, 4 waves (2x2 of 64x32) ----------------
// out[4096][1024] = A @ Wot^T + bias ; grid (16, 32) = 512 blocks -> 2 blocks/CU.
__global__ __launch_bounds__(256, 2) void gemm_out_kernel(
    const bf16* __restrict__ A, const bf16* __restrict__ Bt,
    const float* __restrict__ bias, float* __restrict__ outp) {
  __shared__ __align__(16) bf16 As[128 * 64];  // 16 KB
  __shared__ __align__(16) bf16 Bs[64 * 64];   //  8 KB
  const int tid  = threadIdx.x;
  const int lane = tid & 63, wid = tid >> 6;
  const int wr = wid >> 1, wc = wid & 1;
  const int l15 = lane & 15, lhi = lane >> 4;
  const int mbase = blockIdx.y * 128, nbase = blockIdx.x * 64;

  f32x4 acc[4][2] = {};

  const bf16* sa0; const bf16* sa1; const bf16* sa2; const bf16* sa3;
  const bf16* sb0; const bf16* sb1;
  {
    const int iA0 = tid, iA1 = 256 + tid, iA2 = 512 + tid, iA3 = 768 + tid;
    sa0 = A + (size_t)(mbase + (iA0 >> 3)) * D_ + (((iA0 & 7) ^ ((iA0 >> 3) & 7)) * 8);
    sa1 = A + (size_t)(mbase + (iA1 >> 3)) * D_ + (((iA1 & 7) ^ ((iA1 >> 3) & 7)) * 8);
    sa2 = A + (size_t)(mbase + (iA2 >> 3)) * D_ + (((iA2 & 7) ^ ((iA2 >> 3) & 7)) * 8);
    sa3 = A + (size_t)(mbase + (iA3 >> 3)) * D_ + (((iA3 & 7) ^ ((iA3 >> 3) & 7)) * 8);
    sb0 = Bt + (size_t)(nbase + (iA0 >> 3)) * D_ + (((iA0 & 7) ^ ((iA0 >> 3) & 7)) * 8);
    sb1 = Bt + (size_t)(nbase + (iA1 >> 3)) * D_ + (((iA1 & 7) ^ ((iA1 >> 3) & 7)) * 8);
  }
  const int ub = wid * 1024;

  for (int kt = 0; kt < D_; kt += 64) {
    gld_lds16(sa0 + kt, (char*)As + ub);
    gld_lds16(sa1 + kt, (char*)As + 4096 + ub);
    gld_lds16(sa2 + kt, (char*)As + 8192 + ub);
    gld_lds16(sa3 + kt, (char*)As + 12288 + ub);
    gld_lds16(sb0 + kt, (char*)Bs + ub);
    gld_lds16(sb1 + kt, (char*)Bs + 4096 + ub);
    __syncthreads();

    const int rsw = l15 & 7;
    bf16x8 af[4][2], bfv[2][2];
#pragma unroll
    for (int m = 0; m < 4; ++m)
#pragma unroll
      for (int kk = 0; kk < 2; ++kk)
        af[m][kk] = *reinterpret_cast<const bf16x8*>(
            (const char*)As + (wr * 64 + m * 16 + l15) * 128 + (((kk * 4 + lhi) ^ rsw) * 16));
#pragma unroll
    for (int n = 0; n < 2; ++n)
#pragma unroll
      for (int kk = 0; kk < 2; ++kk)
        bfv[n][kk] = *reinterpret_cast<const bf16x8*>(
            (const char*)Bs + (wc * 32 + n * 16 + l15) * 128 + (((kk * 4 + lhi) ^ rsw) * 16));
#pragma unroll
    for (int m = 0; m < 4; ++m)
#pragma unroll
      for (int n = 0; n < 2; ++n)
#pragma unroll
        for (int kk = 0; kk < 2; ++kk)
          acc[m][n] = MFMA16(af[m][kk], bfv[n][kk], acc[m][n]);
    __syncthreads();
  }

#pragma unroll
  for (int n = 0; n < 2; ++n) {
    const int col = nbase + wc * 32 + n * 16 + l15;
    const float bv_ = bias[col];
#pragma unroll
    for (int m = 0; m < 4; ++m)
#pragma unroll
      for (int j = 0; j < 4; ++j) {
        const int row = mbase + wr * 64 + m * 16 + lhi * 4 + j;
        outp[(size_t)row * D_ + col] = acc[m][n][j] + bv_;
      }
  }
}

// ---------------- flash attention (causal): 8-wave blocks, KV=128 per round ----------------
// Block = 8 waves (512 thr). Intra-block causal pairing: waves 0-3 own q-tile p,
// waves 4-7 own q-tile 31-p (64-row tiles). Each round stages a 128-wide K/V slab.
// V ds_reads issued EARLY (right after QK^T) so their latency hides under the
// softmax VALU chain (T14 issue-early/consume-late; VGPR headroom allows it).
// Staging addresses HOISTED; softmax exp2 via raw v_exp_f32; defer-max (T13, THR=8).
// SWAPPED S^T = mfma(K,Q); P A-fragments built in registers (cvt_pk + shfl_xor(16)),
// kv-chunk permutation pi(lhi)=bitswap applied to P and V fragments.
// K LDS [128 rows][8 chunks] slot c^(r&7); V LDS [64 rows][16 chunks] slot c^(r&15).
// T5: setprio(1) around MFMA clusters.
__global__ __launch_bounds__(512, 4) void attn_kernel(const bf16* __restrict__ Q,
                                                      const bf16* __restrict__ Kg,
                                                      const bf16* __restrict__ Vt,
                                                      bf16* __restrict__ Mg) {
  __shared__ __align__(16) bf16 Kl[2][128 * 64];
  __shared__ __align__(16) bf16 Vl[2][64 * 128];
  const int tid = threadIdx.x, lane = tid & 63, wid = tid >> 6;
  const int l15 = lane & 15, lhi = lane >> 4;
  const int p  = blockIdx.x & 15;             // complementary q-tile pair index
  const int bh = blockIdx.x >> 4;             // adjacent bids share bh -> K/V L2 locality
  const int half = wid >> 2, w4 = wid & 3;
  const int qtile = half ? (31 - p) : p;
  const int qbase = qtile * 64 + w4 * 16;
  const int b = bh >> 4, h = bh & 15;

  const bf16* Qp = Q  + (size_t)bh * T_ * DK_;
  const bf16* Kp = Kg + (size_t)bh * T_ * DK_;
  const bf16* Vp = Vt + (size_t)bh * DK_ * T_;

  const bf16x8 qf0 = *reinterpret_cast<const bf16x8*>(&Qp[(size_t)(qbase + l15) * DK_ + lhi * 8]);
  const bf16x8 qf1 = *reinterpret_cast<const bf16x8*>(&Qp[(size_t)(qbase + l15) * DK_ + 32 + lhi * 8]);

  bf16x8 onesb;
#pragma unroll
  for (int i = 0; i < 8; ++i) onesb[i] = (__bf16)1.0f;

  f32x4 o[4] = {};
  f32x4 lacc = {};
  float mrow = -1e30f;  // running max for this lane's q-row (q = qbase + l15)

  const int ntr = (33 - p) >> 1;  // 128-wide rounds covering high tile's causal extent

  // hoisted per-thread staging sources (T2 pre-swizzle folded in once)
  const int iA = tid, iB = 512 + tid;
  const bf16* ks0 = Kp + (size_t)(iA >> 3) * DK_ + (((iA & 7) ^ ((iA >> 3) & 7)) * 8);
  const bf16* ks1 = Kp + (size_t)(iB >> 3) * DK_ + (((iB & 7) ^ ((iB >> 3) & 7)) * 8);
  const bf16* vs0 = Vp + (size_t)(iA >> 4) * T_ + (((iA & 15) ^ ((iA >> 4) & 15)) * 8);
  const bf16* vs1 = Vp + (size_t)(iB >> 4) * T_ + (((iB & 15) ^ ((iB >> 4) & 15)) * 8);
  const int ub0 = wid * 1024;           // wave-uniform LDS byte base, it=0
  const int ub1 = 8192 + wid * 1024;    // it=1

  // stage round 0 into buffer 0
  gld_lds16(ks0, (char*)Kl[0] + ub0);
  gld_lds16(ks1, (char*)Kl[0] + ub1);
  gld_lds16(vs0, (char*)Vl[0] + ub0);
  gld_lds16(vs1, (char*)Vl[0] + ub1);
  ks0 += 128 * DK_; ks1 += 128 * DK_; vs0 += 128; vs1 += 128;
  __syncthreads();

  for (int rnd = 0; rnd < ntr; ++rnd) {
    const int cur = rnd & 1;
    const char* Kb_ = cur ? (const char*)Kl[1] : (const char*)Kl[0];
    const char* Vb_ = cur ? (const char*)Vl[1] : (const char*)Vl[0];
    if (rnd + 1 < ntr) {  // stage next slab into the other buffer
      char* Kn = cur ? (char*)Kl[0] : (char*)Kl[1];
      char* Vn = cur ? (char*)Vl[0] : (char*)Vl[1];
      gld_lds16(ks0, Kn + ub0);
      gld_lds16(ks1, Kn + ub1);
      gld_lds16(vs0, Vn + ub0);
      gld_lds16(vs1, Vn + ub1);
      ks0 += 128 * DK_; ks1 += 128 * DK_; vs0 += 128; vs1 += 128;
    }

#pragma unroll
    for (int sub = 0; sub < 2; ++sub) {
      const int kv0 = rnd * 128 + sub * 64;
      if (kv0 <= qbase + 15) {  // wave-uniform: wave has live columns in this sub-tile
        // ---- S^T = K Q^T : lane holds q=l15; rows kv = kv0 + s*16 + lhi*4 + j
        f32x4 sv[4];
        __builtin_amdgcn_s_setprio(1);
#pragma unroll
        for (int s = 0; s < 4; ++s) {
          const int cbase = kv0 + s * 16;
          if (cbase <= qbase + 15) {
            const int row = sub * 64 + s * 16 + l15;  // row & 7 == l15 & 7
            const int rsw = l15 & 7;
            const bf16x8 k0 = *reinterpret_cast<const bf16x8*>(Kb_ + row * 128 + ((lhi       ^ rsw) * 16));
            const bf16x8 k1 = *reinterpret_cast<const bf16x8*>(Kb_ + row * 128 + (((4 + lhi) ^ rsw) * 16));
            f32x4 z = {};
            z = MFMA16(k0, qf0, z);          // swapped operand order
            sv[s] = MFMA16(k1, qf1, z);
          } else {
#pragma unroll
            for (int j = 0; j < 4; ++j) sv[s][j] = -1e30f;
          }
        }
        __builtin_amdgcn_s_setprio(0);

        // ---- V fragments from LDS, ISSUED EARLY (latency hides under softmax).
        // kv-chunk permutation pi(lhi) applied (matches P fragment build below).
        const int pl = ((lhi & 1) << 1) | (lhi >> 1);
        bf16x8 vf[8];
#pragma unroll
        for (int d = 0; d < 4; ++d) {
          const int rowv = d * 16 + l15;  // rowv & 15 == l15
#pragma unroll
          for (int s2 = 0; s2 < 2; ++s2) {
            const int cread = sub * 8 + s2 * 4 + pl;
            vf[d * 2 + s2] = *reinterpret_cast<const bf16x8*>(
                Vb_ + rowv * 256 + ((cread ^ l15) * 16));
          }
        }

        // ---- causal mask (kv = row, q = col): only the diagonal-straddling s-tile
#pragma unroll
        for (int s = 0; s < 4; ++s) {
          const int cbase = kv0 + s * 16;
          if (cbase <= qbase + 15 && cbase + 15 > qbase) {
            const int r = qbase + l15;
#pragma unroll
            for (int j = 0; j < 4; ++j) {
              const int c = cbase + lhi * 4 + j;
              sv[s][j] = (c <= r) ? sv[s][j] : -1e30f;
            }
          }
        }

        // ---- online softmax (exp2 domain), defer-max (T13): in-lane max only
        float ml = sv[0][0];
#pragma unroll
        for (int s = 0; s < 4; ++s)
#pragma unroll
          for (int j = 0; j < 4; ++j) ml = fmaxf(ml, sv[s][j]);

        if (__any(ml > mrow + 8.0f)) {
          float mx = ml;
          mx = fmaxf(mx, __shfl_xor(mx, 16, 64));
          mx = fmaxf(mx, __shfl_xor(mx, 32, 64));
          const float mn = fmaxf(mrow, mx);
          const float sc = FEXP2(mrow - mn);
          mrow = mn;
          // broadcast sc into O-layout rows: row q' = lhi*4 + j lives in lane q'
          const int sci = __float_as_int(sc);
#pragma unroll
          for (int j = 0; j < 4; ++j) {
            const float scj = __int_as_float(
                __builtin_amdgcn_ds_bpermute((lhi * 4 + j) * 4, sci));
            lacc[j] *= scj;
            o[0][j] *= scj; o[1][j] *= scj; o[2][j] *= scj; o[3][j] *= scj;
          }
        }
#pragma unroll
        for (int s = 0; s < 4; ++s)
#pragma unroll
          for (int j = 0; j < 4; ++j) sv[s][j] = FEXP2(sv[s][j] - mrow);

        // ---- P A-fragments in registers (no LDS round-trip).
        // Lane's k-slot chunk holds kv chunk pi(lhi), pi = [0,2,1,3] (bitswap).
        const bool oddl = (lhi & 1) != 0;
        bf16x8 pf[2];
#pragma unroll
        for (int hh = 0; hh < 2; ++hh) {
          const uint32_t u0l = cvtpk_bf16(sv[2 * hh][0], sv[2 * hh][1]);
          const uint32_t u0h = cvtpk_bf16(sv[2 * hh][2], sv[2 * hh][3]);
          const uint32_t u1l = cvtpk_bf16(sv[2 * hh + 1][0], sv[2 * hh + 1][1]);
          const uint32_t u1h = cvtpk_bf16(sv[2 * hh + 1][2], sv[2 * hh + 1][3]);
          const uint32_t sl = oddl ? u0l : u1l;
          const uint32_t sh = oddl ? u0h : u1h;
          const uint32_t rl = (uint32_t)__shfl_xor((int)sl, 16, 64);
          const uint32_t rh = (uint32_t)__shfl_xor((int)sh, 16, 64);
          union { uint32_t w[4]; bf16x8 v; } fr;
          fr.w[0] = oddl ? rl : u0l;
          fr.w[1] = oddl ? rh : u0h;
          fr.w[2] = oddl ? u1l : rl;
          fr.w[3] = oddl ? u1h : rh;
          pf[hh] = fr.v;
        }

        // ---- O += P V ; row-sums l += P 1 (same C layout & rescale as O)
        __builtin_amdgcn_s_setprio(1);
#pragma unroll
        for (int d = 0; d < 4; ++d) {
          o[d] = MFMA16(pf[0], vf[d * 2 + 0], o[d]);
          o[d] = MFMA16(pf[1], vf[d * 2 + 1], o[d]);
        }
        lacc = MFMA16(pf[0], onesb, lacc);
        lacc = MFMA16(pf[1], onesb, lacc);
        __builtin_amdgcn_s_setprio(0);
      }
    }

    __syncthreads();  // drains vmcnt (next slab staged) + orders buffer reuse
  }

#pragma unroll
  for (int j = 0; j < 4; ++j) {
    const float inv = 1.0f / lacc[j];
    const int tq = qbase + lhi * 4 + j;
#pragma unroll
    for (int d = 0; d < 4; ++d)
      Mg[((size_t)b * T_ + tq) * D_ + h * DK_ + d * 16 + l15] = __float2bfloat16(o[d][j] * inv);
  }
}

// ---------------- launch ----------------
extern "C" void kernel_launch(void* const* d_in, const int* in_sizes, int n_in,
                              void* d_out, int out_size, void* d_ws, size_t ws_size,
                              hipStream_t stream) {
  (void)in_sizes; (void)n_in; (void)out_size; (void)ws_size;
  const float* x  = (const float*)d_in[0];
  const float* Wq = (const float*)d_in[1];
  const float* bq = (const float*)d_in[2];
  const float* Wk = (const float*)d_in[3];
  const float* bk = (const float*)d_in[4];
  const float* Wv = (const float*)d_in[5];
  const float* bv = (const float*)d_in[6];
  const float* Wo = (const float*)d_in[7];
  const float* bo = (const float*)d_in[8];
  float* out = (float*)d_out;

  // workspace layout (40 MB): Mg aliases xb (xb dead after QKV GEMM, attn runs after)
  char* ws = (char*)d_ws;
  bf16* xb  = (bf16*)(ws);                       // 8 MB [4096][1024]
  bf16* Mg  = (bf16*)(ws);                       // 8 MB [4096][1024] (alias, written by attn)
  bf16* Wt  = (bf16*)(ws + (size_t)( 8u << 20)); // 6 MB [3072][1024] (Wq|Wk|Wv transposed)
  bf16* Wot = (bf16*)(ws + (size_t)(14u << 20)); // 2 MB [1024][1024] (Wo transposed)
  bf16* Qb  = (bf16*)(ws + (size_t)(16u << 20)); // 8 MB [32][2048][64]
  bf16* Kb  = (bf16*)(ws + (size_t)(24u << 20)); // 8 MB [32][2048][64]
  bf16* Vt  = (bf16*)(ws + (size_t)(32u << 20)); // 8 MB [32][64][2048]

  pack_all_kernel<<<5120, 256, 0, stream>>>(x, Wq, Wk, Wv, Wo, xb, Wt, Wot);
  // fused QKV: C[4096][3072] = xb @ [Wq|Wk|Wv]
  gemm_qkv_kernel<<<dim3(24, 32), 256, 0, stream>>>(xb, Wt, bq, bk, bv, Qb, Kb, Vt);
  attn_kernel<<<dim3(512), 512, 0, stream>>>(Qb, Kb, Vt, Mg);
  // out[4096][1024] = Mg @ Wo + bo
  gemm_out_kernel<<<dim3(16, 32), 256, 0, stream>>>(Mg, Wot, bo, out);
}

// Round 17
// 98.365 us; speedup vs baseline: 1.2007x; 1.0013x over previous
//
#include <hip/hip_runtime.h>
#include <hip/hip_bf16.h>
#include <cstdint>
#include <cstddef>

// MHA forward: B=2, T=2048, D=1024, H=16, dk=64. fp32 in/out, bf16 MFMA internal.
#define B_  2
#define T_  2048
#define D_  1024
#define H_  16
#define DK_ 64

typedef __hip_bfloat16 bf16;
typedef __bf16 bf16x8 __attribute__((ext_vector_type(8)));  // MFMA A/B frag (4 VGPRs)
typedef float  f32x4  __attribute__((ext_vector_type(4)));  // MFMA C/D frag

#define MFMA16(a, b, c) __builtin_amdgcn_mfma_f32_16x16x32_bf16((a), (b), (c), 0, 0, 0)

// Q production scale: 1/sqrt(64) * log2(e)  (softmax done in exp2 domain)
#define SCALE_Q 0.1803368801111137f

// fast exp2: raw v_exp_f32 (no denorm fixup; inputs are either ~[-30,8] or -inf-ish)
#if defined(__has_builtin)
#if __has_builtin(__builtin_amdgcn_exp2f)
#define FEXP2(x) __builtin_amdgcn_exp2f(x)
#endif
#endif
#ifndef FEXP2
__device__ static inline float fexp2_asm(float x) {
  float r; asm("v_exp_f32 %0, %1" : "=v"(r) : "v"(x)); return r;
}
#define FEXP2(x) fexp2_asm(x)
#endif

__device__ static inline void gld_lds16(const void* g, void* l) {
  // async global->LDS, 16B per lane; LDS dest is wave-uniform base + lane*16
  __builtin_amdgcn_global_load_lds((const __attribute__((address_space(1))) void*)g,
                                   (__attribute__((address_space(3))) void*)l, 16, 0, 0);
}

__device__ static inline ushort f2bu(float x) {
  union { bf16 h; ushort u; } c;
  c.h = __float2bfloat16(x);
  return c.u;
}

__device__ static inline uint32_t cvtpk_bf16(float lo, float hi) {
  uint32_t r;
  asm volatile("v_cvt_pk_bf16_f32 %0, %1, %2" : "=v"(r) : "v"(lo), "v"(hi));
  return r;  // low16 = bf16(lo), high16 = bf16(hi)
}

// ---------------- fused pack: x fp32->bf16 (bids 0..4095) + W transpose (bids 4096..5119) ----------------
__global__ __launch_bounds__(256) void pack_all_kernel(const float* __restrict__ x,
                                                       const float* __restrict__ Wq,
                                                       const float* __restrict__ Wk,
                                                       const float* __restrict__ Wv,
                                                       const float* __restrict__ Wo,
                                                       bf16* __restrict__ xb,
                                                       bf16* __restrict__ Wt,    // [3072][1024]
                                                       bf16* __restrict__ Wot) { // [1024][1024]
  __shared__ bf16 t[64][68];  // stride 68 (136B): 8B-aligned rows, 2-way bank alias (free)
  const int bid = blockIdx.x;
  const int tid = threadIdx.x;
  if (bid < 4096) {
    // ---- pack x: 4 fp32 -> 4 bf16 per thread
    const int i = bid * 256 + tid;
    const float4 v = reinterpret_cast<const float4*>(x)[i];
    union { ushort4 u; bf16 h[4]; } c;
    c.h[0] = __float2bfloat16(v.x);
    c.h[1] = __float2bfloat16(v.y);
    c.h[2] = __float2bfloat16(v.z);
    c.h[3] = __float2bfloat16(v.w);
    reinterpret_cast<ushort4*>(xb)[i] = c.u;
    return;
  }
  // ---- pack W: transpose+convert 64x64 tiles (vectorized: float4 reads, 8B stores)
  const int wb  = bid - 4096;
  const int mat  = wb >> 8;        // 0..3 : Wq,Wk,Wv,Wo
  const int tile = wb & 255;       // 16x16 tiles of 64x64
  const int tr = tile >> 4, tc = tile & 15;
  const float* W = (mat == 0) ? Wq : (mat == 1) ? Wk : (mat == 2) ? Wv : Wo;
#pragma unroll
  for (int i = 0; i < 4; ++i) {
    const int idx = i * 256 + tid;
    const int r = idx >> 4, c4 = (idx & 15) * 4;
    const float4 v = *reinterpret_cast<const float4*>(&W[(size_t)(tr * 64 + r) * D_ + tc * 64 + c4]);
    union { ushort u[4]; uint2 q; } pk;
    pk.u[0] = f2bu(v.x); pk.u[1] = f2bu(v.y); pk.u[2] = f2bu(v.z); pk.u[3] = f2bu(v.w);
    *reinterpret_cast<uint2*>(&t[r][c4]) = pk.q;
  }
  __syncthreads();
  bf16* dst = (mat == 3) ? Wot : (Wt + (size_t)mat * D_ * D_);
#pragma unroll
  for (int i = 0; i < 4; ++i) {
    const int idx = i * 256 + tid;
    const int n = idx >> 4, kg = (idx & 15) * 4;
    union { ushort u[4]; uint2 q; } pk;
#pragma unroll
    for (int j = 0; j < 4; ++j) pk.u[j] = reinterpret_cast<const ushort&>(t[kg + j][n]);
    *reinterpret_cast<uint2*>(&dst[(size_t)(tc * 64 + n) * D_ + tr * 64 + kg]) = pk.q;
  }
}

// ---------------- QKV GEMM: 128x128 bf16, BK=64, 4 waves (2x2 of 64x64) ----------------
// A: [M][K] row-major bf16.  Bt: [N][K] row-major bf16 (B transposed).
// BK=64 halves barrier count (16 rounds x 32 MFMA). LDS rows of 8x16B chunks,
// slot c^(r&7) (T2 swizzle via pre-swizzled source; reads XOR l15&7).
// Epilogue -> Qb/Kb [BH][T][64], Vt [BH][64][T] (V packed 4t/store), + bias;
// Q scaled by SCALE_Q.
__global__ __launch_bounds__(256, 3) void gemm_qkv_kernel(
    const bf16* __restrict__ A, const bf16* __restrict__ Bt,
    const float* __restrict__ bias0, const float* __restrict__ bias1,
    const float* __restrict__ bias2,
    bf16* __restrict__ Qb, bf16* __restrict__ Kb, bf16* __restrict__ Vt) {
  __shared__ __align__(16) bf16 As[128 * 64];  // 16 KB
  __shared__ __align__(16) bf16 Bs[128 * 64];  // 16 KB
  const int tid  = threadIdx.x;
  const int lane = tid & 63, wid = tid >> 6;
  const int wr = wid >> 1, wc = wid & 1;
  const int l15 = lane & 15, lhi = lane >> 4;
  const int mbase = blockIdx.y * 128, nbase = blockIdx.x * 128;

  f32x4 acc[4][4] = {};

  const bf16* sa[4]; const bf16* sb[4];
#pragma unroll
  for (int it = 0; it < 4; ++it) {
    const int idx = it * 256 + tid;
    const int r = idx >> 3, cs = ((idx & 7) ^ ((idx >> 3) & 7)) * 8;
    sa[it] = A  + (size_t)(mbase + r) * D_ + cs;
    sb[it] = Bt + (size_t)(nbase + r) * D_ + cs;
  }
  const int ub = wid * 1024;  // wave-uniform LDS byte base within each 256-chunk group

  for (int kt = 0; kt < D_; kt += 64) {
#pragma unroll
    for (int it = 0; it < 4; ++it) {
      gld_lds16(sa[it] + kt, (char*)As + it * 4096 + ub);
      gld_lds16(sb[it] + kt, (char*)Bs + it * 4096 + ub);
    }
    __syncthreads();  // compiler drains vmcnt before barrier

    const int rsw = l15 & 7;
    bf16x8 af[4][2], bfv[4][2];
#pragma unroll
    for (int m = 0; m < 4; ++m)
#pragma unroll
      for (int kk = 0; kk < 2; ++kk)
        af[m][kk] = *reinterpret_cast<const bf16x8*>(
            (const char*)As + (wr * 64 + m * 16 + l15) * 128 + (((kk * 4 + lhi) ^ rsw) * 16));
#pragma unroll
    for (int n = 0; n < 4; ++n)
#pragma unroll
      for (int kk = 0; kk < 2; ++kk)
        bfv[n][kk] = *reinterpret_cast<const bf16x8*>(
            (const char*)Bs + (wc * 64 + n * 16 + l15) * 128 + (((kk * 4 + lhi) ^ rsw) * 16));
#pragma unroll
    for (int m = 0; m < 4; ++m)
#pragma unroll
      for (int n = 0; n < 4; ++n)
#pragma unroll
        for (int kk = 0; kk < 2; ++kk)
          acc[m][n] = MFMA16(af[m][kk], bfv[n][kk], acc[m][n]);
    __syncthreads();
  }

  // epilogue: D layout col = lane&15, row = (lane>>4)*4 + j
#pragma unroll
  for (int n = 0; n < 4; ++n) {
    const int col = nbase + wc * 64 + n * 16 + l15;
    const int seg  = col >> 10;      // 0=Q 1=K 2=V (uniform per block)
    const int ncol = col & 1023;
    const float* bias = (seg == 0) ? bias0 : (seg == 1) ? bias1 : bias2;
    const float bv_ = bias[ncol];
    const int h = ncol >> 6, dk = ncol & 63;
    if (seg == 2) {
      // V: pack 4 consecutive t (j=0..3) into one 8B store
#pragma unroll
      for (int m = 0; m < 4; ++m) {
        const int t0 = mbase + wr * 64 + m * 16 + lhi * 4;  // multiple of 4
        const int b = t0 >> 11, t = t0 & 2047;
        union { ushort u[4]; uint2 v; } pk;
#pragma unroll
        for (int j = 0; j < 4; ++j) pk.u[j] = f2bu(acc[m][n][j] + bv_);
        *reinterpret_cast<uint2*>(&Vt[((size_t)(b * H_ + h) * DK_ + dk) * T_ + t]) = pk.v;
      }
    } else {
#pragma unroll
      for (int m = 0; m < 4; ++m) {
#pragma unroll
        for (int j = 0; j < 4; ++j) {
          const int row = mbase + wr * 64 + m * 16 + lhi * 4 + j;
          const int b = row >> 11, t = row & 2047;
          const int bh = b * H_ + h;
          float outv = acc[m][n][j] + bv_;
          if (seg == 0) outv *= SCALE_Q;  // fold 1/sqrt(dk)*log2(e) into Q
          const bf16 hv = __float2bfloat16(outv);
          if (seg == 0) Qb[((size_t)bh * T_ + t) * DK_ + dk] = hv;
          else          Kb[((size_t)bh * T_ + t) * DK_ + dk] = hv;
        }
      }
    }
  }
}

// ---------------- out GEMM: 128x64 tile, BK=64, 4 waves (2x2 of 64x32) ----------------
// out[4096][1024] = A @ Wot^T + bias ; grid (16, 32) = 512 blocks -> 2 blocks/CU.
__global__ __launch_bounds__(256, 2) void gemm_out_kernel(
    const bf16* __restrict__ A, const bf16* __restrict__ Bt,
    const float* __restrict__ bias, float* __restrict__ outp) {
  __shared__ __align__(16) bf16 As[128 * 64];  // 16 KB
  __shared__ __align__(16) bf16 Bs[64 * 64];   //  8 KB
  const int tid  = threadIdx.x;
  const int lane = tid & 63, wid = tid >> 6;
  const int wr = wid >> 1, wc = wid & 1;
  const int l15 = lane & 15, lhi = lane >> 4;
  const int mbase = blockIdx.y * 128, nbase = blockIdx.x * 64;

  f32x4 acc[4][2] = {};

  const bf16* sa0; const bf16* sa1; const bf16* sa2; const bf16* sa3;
  const bf16* sb0; const bf16* sb1;
  {
    const int iA0 = tid, iA1 = 256 + tid, iA2 = 512 + tid, iA3 = 768 + tid;
    sa0 = A + (size_t)(mbase + (iA0 >> 3)) * D_ + (((iA0 & 7) ^ ((iA0 >> 3) & 7)) * 8);
    sa1 = A + (size_t)(mbase + (iA1 >> 3)) * D_ + (((iA1 & 7) ^ ((iA1 >> 3) & 7)) * 8);
    sa2 = A + (size_t)(mbase + (iA2 >> 3)) * D_ + (((iA2 & 7) ^ ((iA2 >> 3) & 7)) * 8);
    sa3 = A + (size_t)(mbase + (iA3 >> 3)) * D_ + (((iA3 & 7) ^ ((iA3 >> 3) & 7)) * 8);
    sb0 = Bt + (size_t)(nbase + (iA0 >> 3)) * D_ + (((iA0 & 7) ^ ((iA0 >> 3) & 7)) * 8);
    sb1 = Bt + (size_t)(nbase + (iA1 >> 3)) * D_ + (((iA1 & 7) ^ ((iA1 >> 3) & 7)) * 8);
  }
  const int ub = wid * 1024;

  for (int kt = 0; kt < D_; kt += 64) {
    gld_lds16(sa0 + kt, (char*)As + ub);
    gld_lds16(sa1 + kt, (char*)As + 4096 + ub);
    gld_lds16(sa2 + kt, (char*)As + 8192 + ub);
    gld_lds16(sa3 + kt, (char*)As + 12288 + ub);
    gld_lds16(sb0 + kt, (char*)Bs + ub);
    gld_lds16(sb1 + kt, (char*)Bs + 4096 + ub);
    __syncthreads();

    const int rsw = l15 & 7;
    bf16x8 af[4][2], bfv[2][2];
#pragma unroll
    for (int m = 0; m < 4; ++m)
#pragma unroll
      for (int kk = 0; kk < 2; ++kk)
        af[m][kk] = *reinterpret_cast<const bf16x8*>(
            (const char*)As + (wr * 64 + m * 16 + l15) * 128 + (((kk * 4 + lhi) ^ rsw) * 16));
#pragma unroll
    for (int n = 0; n < 2; ++n)
#pragma unroll
      for (int kk = 0; kk < 2; ++kk)
        bfv[n][kk] = *reinterpret_cast<const bf16x8*>(
            (const char*)Bs + (wc * 32 + n * 16 + l15) * 128 + (((kk * 4 + lhi) ^ rsw) * 16));
#pragma unroll
    for (int m = 0; m < 4; ++m)
#pragma unroll
      for (int n = 0; n < 2; ++n)
#pragma unroll
        for (int kk = 0; kk < 2; ++kk)
          acc[m][n] = MFMA16(af[m][kk], bfv[n][kk], acc[m][n]);
    __syncthreads();
  }

#pragma unroll
  for (int n = 0; n < 2; ++n) {
    const int col = nbase + wc * 32 + n * 16 + l15;
    const float bv_ = bias[col];
#pragma unroll
    for (int m = 0; m < 4; ++m)
#pragma unroll
      for (int j = 0; j < 4; ++j) {
        const int row = mbase + wr * 64 + m * 16 + lhi * 4 + j;
        outp[(size_t)row * D_ + col] = acc[m][n][j] + bv_;
      }
  }
}

// ---------------- flash attention (causal): 8-wave blocks, KV=128 per round ----------------
// REVERTED to the round-15-passing structure (the K-prefetch restructure NaN'd).
// Block = 8 waves (512 thr). Intra-block causal pairing: waves 0-3 own q-tile p,
// waves 4-7 own q-tile 31-p (64-row tiles). Each round stages a 128-wide K/V slab.
// V ds_reads issued EARLY (right after QK^T) so their latency hides under the
// softmax VALU chain (T14). Staging addresses HOISTED; softmax exp2 via raw
// v_exp_f32; defer-max (T13, THR=8). SWAPPED S^T = mfma(K,Q); P A-fragments built
// in registers (cvt_pk + shfl_xor(16)), kv-chunk permutation pi(lhi)=bitswap applied
// to P and V fragments. K LDS [128 rows][8 chunks] slot c^(r&7); V LDS [64 rows]
// [16 chunks] slot c^(r&15). T5: setprio(1) around MFMA clusters.
__global__ __launch_bounds__(512, 4) void attn_kernel(const bf16* __restrict__ Q,
                                                      const bf16* __restrict__ Kg,
                                                      const bf16* __restrict__ Vt,
                                                      bf16* __restrict__ Mg) {
  __shared__ __align__(16) bf16 Kl[2][128 * 64];
  __shared__ __align__(16) bf16 Vl[2][64 * 128];
  const int tid = threadIdx.x, lane = tid & 63, wid = tid >> 6;
  const int l15 = lane & 15, lhi = lane >> 4;
  const int p  = blockIdx.x & 15;             // complementary q-tile pair index
  const int bh = blockIdx.x >> 4;             // adjacent bids share bh -> K/V L2 locality
  const int half = wid >> 2, w4 = wid & 3;
  const int qtile = half ? (31 - p) : p;
  const int qbase = qtile * 64 + w4 * 16;
  const int b = bh >> 4, h = bh & 15;

  const bf16* Qp = Q  + (size_t)bh * T_ * DK_;
  const bf16* Kp = Kg + (size_t)bh * T_ * DK_;
  const bf16* Vp = Vt + (size_t)bh * DK_ * T_;

  const bf16x8 qf0 = *reinterpret_cast<const bf16x8*>(&Qp[(size_t)(qbase + l15) * DK_ + lhi * 8]);
  const bf16x8 qf1 = *reinterpret_cast<const bf16x8*>(&Qp[(size_t)(qbase + l15) * DK_ + 32 + lhi * 8]);

  bf16x8 onesb;
#pragma unroll
  for (int i = 0; i < 8; ++i) onesb[i] = (__bf16)1.0f;

  f32x4 o[4] = {};
  f32x4 lacc = {};
  float mrow = -1e30f;  // running max for this lane's q-row (q = qbase + l15)

  const int ntr = (33 - p) >> 1;  // 128-wide rounds covering high tile's causal extent

  // hoisted per-thread staging sources (T2 pre-swizzle folded in once)
  const int iA = tid, iB = 512 + tid;
  const bf16* ks0 = Kp + (size_t)(iA >> 3) * DK_ + (((iA & 7) ^ ((iA >> 3) & 7)) * 8);
  const bf16* ks1 = Kp + (size_t)(iB >> 3) * DK_ + (((iB & 7) ^ ((iB >> 3) & 7)) * 8);
  const bf16* vs0 = Vp + (size_t)(iA >> 4) * T_ + (((iA & 15) ^ ((iA >> 4) & 15)) * 8);
  const bf16* vs1 = Vp + (size_t)(iB >> 4) * T_ + (((iB & 15) ^ ((iB >> 4) & 15)) * 8);
  const int ub0 = wid * 1024;           // wave-uniform LDS byte base, it=0
  const int ub1 = 8192 + wid * 1024;    // it=1

  // stage round 0 into buffer 0
  gld_lds16(ks0, (char*)Kl[0] + ub0);
  gld_lds16(ks1, (char*)Kl[0] + ub1);
  gld_lds16(vs0, (char*)Vl[0] + ub0);
  gld_lds16(vs1, (char*)Vl[0] + ub1);
  ks0 += 128 * DK_; ks1 += 128 * DK_; vs0 += 128; vs1 += 128;
  __syncthreads();

  for (int rnd = 0; rnd < ntr; ++rnd) {
    const int cur = rnd & 1;
    const char* Kb_ = cur ? (const char*)Kl[1] : (const char*)Kl[0];
    const char* Vb_ = cur ? (const char*)Vl[1] : (const char*)Vl[0];
    if (rnd + 1 < ntr) {  // stage next slab into the other buffer
      char* Kn = cur ? (char*)Kl[0] : (char*)Kl[1];
      char* Vn = cur ? (char*)Vl[0] : (char*)Vl[1];
      gld_lds16(ks0, Kn + ub0);
      gld_lds16(ks1, Kn + ub1);
      gld_lds16(vs0, Vn + ub0);
      gld_lds16(vs1, Vn + ub1);
      ks0 += 128 * DK_; ks1 += 128 * DK_; vs0 += 128; vs1 += 128;
    }

#pragma unroll
    for (int sub = 0; sub < 2; ++sub) {
      const int kv0 = rnd * 128 + sub * 64;
      if (kv0 <= qbase + 15) {  // wave-uniform: wave has live columns in this sub-tile
        // ---- S^T = K Q^T : lane holds q=l15; rows kv = kv0 + s*16 + lhi*4 + j
        f32x4 sv[4];
        __builtin_amdgcn_s_setprio(1);
#pragma unroll
        for (int s = 0; s < 4; ++s) {
          const int cbase = kv0 + s * 16;
          if (cbase <= qbase + 15) {
            const int row = sub * 64 + s * 16 + l15;  // row & 7 == l15 & 7
            const int rsw = l15 & 7;
            const bf16x8 k0 = *reinterpret_cast<const bf16x8*>(Kb_ + row * 128 + ((lhi       ^ rsw) * 16));
            const bf16x8 k1 = *reinterpret_cast<const bf16x8*>(Kb_ + row * 128 + (((4 + lhi) ^ rsw) * 16));
            f32x4 z = {};
            z = MFMA16(k0, qf0, z);          // swapped operand order
            sv[s] = MFMA16(k1, qf1, z);
          } else {
#pragma unroll
            for (int j = 0; j < 4; ++j) sv[s][j] = -1e30f;
          }
        }
        __builtin_amdgcn_s_setprio(0);

        // ---- V fragments from LDS, ISSUED EARLY (latency hides under softmax).
        // kv-chunk permutation pi(lhi) applied (matches P fragment build below).
        const int pl = ((lhi & 1) << 1) | (lhi >> 1);
        bf16x8 vf[8];
#pragma unroll
        for (int d = 0; d < 4; ++d) {
          const int rowv = d * 16 + l15;  // rowv & 15 == l15
#pragma unroll
          for (int s2 = 0; s2 < 2; ++s2) {
            const int cread = sub * 8 + s2 * 4 + pl;
            vf[d * 2 + s2] = *reinterpret_cast<const bf16x8*>(
                Vb_ + rowv * 256 + ((cread ^ l15) * 16));
          }
        }

        // ---- causal mask (kv = row, q = col): only the diagonal-straddling s-tile
#pragma unroll
        for (int s = 0; s < 4; ++s) {
          const int cbase = kv0 + s * 16;
          if (cbase <= qbase + 15 && cbase + 15 > qbase) {
            const int r = qbase + l15;
#pragma unroll
            for (int j = 0; j < 4; ++j) {
              const int c = cbase + lhi * 4 + j;
              sv[s][j] = (c <= r) ? sv[s][j] : -1e30f;
            }
          }
        }

        // ---- online softmax (exp2 domain), defer-max (T13): in-lane max only
        float ml = sv[0][0];
#pragma unroll
        for (int s = 0; s < 4; ++s)
#pragma unroll
          for (int j = 0; j < 4; ++j) ml = fmaxf(ml, sv[s][j]);

        if (__any(ml > mrow + 8.0f)) {
          float mx = ml;
          mx = fmaxf(mx, __shfl_xor(mx, 16, 64));
          mx = fmaxf(mx, __shfl_xor(mx, 32, 64));
          const float mn = fmaxf(mrow, mx);
          const float sc = FEXP2(mrow - mn);
          mrow = mn;
          // broadcast sc into O-layout rows: row q' = lhi*4 + j lives in lane q'
          const int sci = __float_as_int(sc);
#pragma unroll
          for (int j = 0; j < 4; ++j) {
            const float scj = __int_as_float(
                __builtin_amdgcn_ds_bpermute((lhi * 4 + j) * 4, sci));
            lacc[j] *= scj;
            o[0][j] *= scj; o[1][j] *= scj; o[2][j] *= scj; o[3][j] *= scj;
          }
        }
#pragma unroll
        for (int s = 0; s < 4; ++s)
#pragma unroll
          for (int j = 0; j < 4; ++j) sv[s][j] = FEXP2(sv[s][j] - mrow);

        // ---- P A-fragments in registers (no LDS round-trip).
        // Lane's k-slot chunk holds kv chunk pi(lhi), pi = [0,2,1,3] (bitswap).
        const bool oddl = (lhi & 1) != 0;
        bf16x8 pf[2];
#pragma unroll
        for (int hh = 0; hh < 2; ++hh) {
          const uint32_t u0l = cvtpk_bf16(sv[2 * hh][0], sv[2 * hh][1]);
          const uint32_t u0h = cvtpk_bf16(sv[2 * hh][2], sv[2 * hh][3]);
          const uint32_t u1l = cvtpk_bf16(sv[2 * hh + 1][0], sv[2 * hh + 1][1]);
          const uint32_t u1h = cvtpk_bf16(sv[2 * hh + 1][2], sv[2 * hh + 1][3]);
          const uint32_t sl = oddl ? u0l : u1l;
          const uint32_t sh = oddl ? u0h : u1h;
          const uint32_t rl = (uint32_t)__shfl_xor((int)sl, 16, 64);
          const uint32_t rh = (uint32_t)__shfl_xor((int)sh, 16, 64);
          union { uint32_t w[4]; bf16x8 v; } fr;
          fr.w[0] = oddl ? rl : u0l;
          fr.w[1] = oddl ? rh : u0h;
          fr.w[2] = oddl ? u1l : rl;
          fr.w[3] = oddl ? u1h : rh;
          pf[hh] = fr.v;
        }

        // ---- O += P V ; row-sums l += P 1 (same C layout & rescale as O)
        __builtin_amdgcn_s_setprio(1);
#pragma unroll
        for (int d = 0; d < 4; ++d) {
          o[d] = MFMA16(pf[0], vf[d * 2 + 0], o[d]);
          o[d] = MFMA16(pf[1], vf[d * 2 + 1], o[d]);
        }
        lacc = MFMA16(pf[0], onesb, lacc);
        lacc = MFMA16(pf[1], onesb, lacc);
        __builtin_amdgcn_s_setprio(0);
      }
    }

    __syncthreads();  // drains vmcnt (next slab staged) + orders buffer reuse
  }

#pragma unroll
  for (int j = 0; j < 4; ++j) {
    const float inv = 1.0f / lacc[j];
    const int tq = qbase + lhi * 4 + j;
#pragma unroll
    for (int d = 0; d < 4; ++d)
      Mg[((size_t)b * T_ + tq) * D_ + h * DK_ + d * 16 + l15] = __float2bfloat16(o[d][j] * inv);
  }
}

// ---------------- launch ----------------
extern "C" void kernel_launch(void* const* d_in, const int* in_sizes, int n_in,
                              void* d_out, int out_size, void* d_ws, size_t ws_size,
                              hipStream_t stream) {
  (void)in_sizes; (void)n_in; (void)out_size; (void)ws_size;
  const float* x  = (const float*)d_in[0];
  const float* Wq = (const float*)d_in[1];
  const float* bq = (const float*)d_in[2];
  const float* Wk = (const float*)d_in[3];
  const float* bk = (const float*)d_in[4];
  const float* Wv = (const float*)d_in[5];
  const float* bv = (const float*)d_in[6];
  const float* Wo = (const float*)d_in[7];
  const float* bo = (const float*)d_in[8];
  float* out = (float*)d_out;

  // workspace layout (40 MB): Mg aliases xb (xb dead after QKV GEMM, attn runs after)
  char* ws = (char*)d_ws;
  bf16* xb  = (bf16*)(ws);                       // 8 MB [4096][1024]
  bf16* Mg  = (bf16*)(ws);                       // 8 MB [4096][1024] (alias, written by attn)
  bf16* Wt  = (bf16*)(ws + (size_t)( 8u << 20)); // 6 MB [3072][1024] (Wq|Wk|Wv transposed)
  bf16* Wot = (bf16*)(ws + (size_t)(14u << 20)); // 2 MB [1024][1024] (Wo transposed)
  bf16* Qb  = (bf16*)(ws + (size_t)(16u << 20)); // 8 MB [32][2048][64]
  bf16* Kb  = (bf16*)(ws + (size_t)(24u << 20)); // 8 MB [32][2048][64]
  bf16* Vt  = (bf16*)(ws + (size_t)(32u << 20)); // 8 MB [32][64][2048]

  pack_all_kernel<<<5120, 256, 0, stream>>>(x, Wq, Wk, Wv, Wo, xb, Wt, Wot);
  // fused QKV: C[4096][3072] = xb @ [Wq|Wk|Wv]
  gemm_qkv_kernel<<<dim3(24, 32), 256, 0, stream>>>(xb, Wt, bq, bk, bv, Qb, Kb, Vt);
  attn_kernel<<<dim3(512), 512, 0, stream>>>(Qb, Kb, Vt, Mg);
  // out[4096][1024] = Mg @ Wo + bo
  gemm_out_kernel<<<dim3(16, 32), 256, 0, stream>>>(Mg, Wot, bo, out);
}

// Round 18
// 96.903 us; speedup vs baseline: 1.2188x; 1.0151x over previous
//
#include <hip/hip_runtime.h>
#include <hip/hip_bf16.h>
#include <cstdint>
#include <cstddef>

// MHA forward: B=2, T=2048, D=1024, H=16, dk=64. fp32 in/out, bf16 MFMA internal.
#define B_  2
#define T_  2048
#define D_  1024
#define H_  16
#define DK_ 64

typedef __hip_bfloat16 bf16;
typedef __bf16 bf16x8 __attribute__((ext_vector_type(8)));  // MFMA A/B frag (4 VGPRs)
typedef float  f32x4  __attribute__((ext_vector_type(4)));  // MFMA C/D frag

#define MFMA16(a, b, c) __builtin_amdgcn_mfma_f32_16x16x32_bf16((a), (b), (c), 0, 0, 0)

// Q production scale: 1/sqrt(64) * log2(e)  (softmax done in exp2 domain)
#define SCALE_Q 0.1803368801111137f

// fast exp2: raw v_exp_f32 (no denorm fixup; inputs are either ~[-30,8] or -inf-ish)
#if defined(__has_builtin)
#if __has_builtin(__builtin_amdgcn_exp2f)
#define FEXP2(x) __builtin_amdgcn_exp2f(x)
#endif
#endif
#ifndef FEXP2
__device__ static inline float fexp2_asm(float x) {
  float r; asm("v_exp_f32 %0, %1" : "=v"(r) : "v"(x)); return r;
}
#define FEXP2(x) fexp2_asm(x)
#endif

__device__ static inline void gld_lds16(const void* g, void* l) {
  // async global->LDS, 16B per lane; LDS dest is wave-uniform base + lane*16
  __builtin_amdgcn_global_load_lds((const __attribute__((address_space(1))) void*)g,
                                   (__attribute__((address_space(3))) void*)l, 16, 0, 0);
}

__device__ static inline ushort f2bu(float x) {
  union { bf16 h; ushort u; } c;
  c.h = __float2bfloat16(x);
  return c.u;
}

__device__ static inline uint32_t cvtpk_bf16(float lo, float hi) {
  uint32_t r;
  asm volatile("v_cvt_pk_bf16_f32 %0, %1, %2" : "=v"(r) : "v"(lo), "v"(hi));
  return r;  // low16 = bf16(lo), high16 = bf16(hi)
}

// ---------------- fused pack: x fp32->bf16 (bids 0..4095) + W transpose (bids 4096..5119) ----------------
__global__ __launch_bounds__(256) void pack_all_kernel(const float* __restrict__ x,
                                                       const float* __restrict__ Wq,
                                                       const float* __restrict__ Wk,
                                                       const float* __restrict__ Wv,
                                                       const float* __restrict__ Wo,
                                                       bf16* __restrict__ xb,
                                                       bf16* __restrict__ Wt,    // [3072][1024]
                                                       bf16* __restrict__ Wot) { // [1024][1024]
  __shared__ bf16 t[64][68];  // stride 68 (136B): 8B-aligned rows, 2-way bank alias (free)
  const int bid = blockIdx.x;
  const int tid = threadIdx.x;
  if (bid < 4096) {
    // ---- pack x: 4 fp32 -> 4 bf16 per thread
    const int i = bid * 256 + tid;
    const float4 v = reinterpret_cast<const float4*>(x)[i];
    union { ushort4 u; bf16 h[4]; } c;
    c.h[0] = __float2bfloat16(v.x);
    c.h[1] = __float2bfloat16(v.y);
    c.h[2] = __float2bfloat16(v.z);
    c.h[3] = __float2bfloat16(v.w);
    reinterpret_cast<ushort4*>(xb)[i] = c.u;
    return;
  }
  // ---- pack W: transpose+convert 64x64 tiles (vectorized: float4 reads, 8B stores)
  const int wb  = bid - 4096;
  const int mat  = wb >> 8;        // 0..3 : Wq,Wk,Wv,Wo
  const int tile = wb & 255;       // 16x16 tiles of 64x64
  const int tr = tile >> 4, tc = tile & 15;
  const float* W = (mat == 0) ? Wq : (mat == 1) ? Wk : (mat == 2) ? Wv : Wo;
#pragma unroll
  for (int i = 0; i < 4; ++i) {
    const int idx = i * 256 + tid;
    const int r = idx >> 4, c4 = (idx & 15) * 4;
    const float4 v = *reinterpret_cast<const float4*>(&W[(size_t)(tr * 64 + r) * D_ + tc * 64 + c4]);
    union { ushort u[4]; uint2 q; } pk;
    pk.u[0] = f2bu(v.x); pk.u[1] = f2bu(v.y); pk.u[2] = f2bu(v.z); pk.u[3] = f2bu(v.w);
    *reinterpret_cast<uint2*>(&t[r][c4]) = pk.q;
  }
  __syncthreads();
  bf16* dst = (mat == 3) ? Wot : (Wt + (size_t)mat * D_ * D_);
#pragma unroll
  for (int i = 0; i < 4; ++i) {
    const int idx = i * 256 + tid;
    const int n = idx >> 4, kg = (idx & 15) * 4;
    union { ushort u[4]; uint2 q; } pk;
#pragma unroll
    for (int j = 0; j < 4; ++j) pk.u[j] = reinterpret_cast<const ushort&>(t[kg + j][n]);
    *reinterpret_cast<uint2*>(&dst[(size_t)(tc * 64 + n) * D_ + tr * 64 + kg]) = pk.q;
  }
}

// ---------------- QKV GEMM: 128x128 bf16, BK=64, 4 waves (2x2 of 64x64) ----------------
// A: [M][K] row-major bf16.  Bt: [N][K] row-major bf16 (B transposed).
// BK=64 halves barrier count (16 rounds x 32 MFMA). LDS rows of 8x16B chunks,
// slot c^(r&7) (T2 swizzle via pre-swizzled source; reads XOR l15&7).
// Epilogue -> Qb/Kb [BH][T][64], Vt [BH][64][T] (V packed 4t/store), + bias;
// Q scaled by SCALE_Q.
__global__ __launch_bounds__(256, 3) void gemm_qkv_kernel(
    const bf16* __restrict__ A, const bf16* __restrict__ Bt,
    const float* __restrict__ bias0, const float* __restrict__ bias1,
    const float* __restrict__ bias2,
    bf16* __restrict__ Qb, bf16* __restrict__ Kb, bf16* __restrict__ Vt) {
  __shared__ __align__(16) bf16 As[128 * 64];  // 16 KB
  __shared__ __align__(16) bf16 Bs[128 * 64];  // 16 KB
  const int tid  = threadIdx.x;
  const int lane = tid & 63, wid = tid >> 6;
  const int wr = wid >> 1, wc = wid & 1;
  const int l15 = lane & 15, lhi = lane >> 4;
  const int mbase = blockIdx.y * 128, nbase = blockIdx.x * 128;

  f32x4 acc[4][4] = {};

  const bf16* sa[4]; const bf16* sb[4];
#pragma unroll
  for (int it = 0; it < 4; ++it) {
    const int idx = it * 256 + tid;
    const int r = idx >> 3, cs = ((idx & 7) ^ ((idx >> 3) & 7)) * 8;
    sa[it] = A  + (size_t)(mbase + r) * D_ + cs;
    sb[it] = Bt + (size_t)(nbase + r) * D_ + cs;
  }
  const int ub = wid * 1024;  // wave-uniform LDS byte base within each 256-chunk group

  for (int kt = 0; kt < D_; kt += 64) {
#pragma unroll
    for (int it = 0; it < 4; ++it) {
      gld_lds16(sa[it] + kt, (char*)As + it * 4096 + ub);
      gld_lds16(sb[it] + kt, (char*)Bs + it * 4096 + ub);
    }
    __syncthreads();  // compiler drains vmcnt before barrier

    const int rsw = l15 & 7;
    bf16x8 af[4][2], bfv[4][2];
#pragma unroll
    for (int m = 0; m < 4; ++m)
#pragma unroll
      for (int kk = 0; kk < 2; ++kk)
        af[m][kk] = *reinterpret_cast<const bf16x8*>(
            (const char*)As + (wr * 64 + m * 16 + l15) * 128 + (((kk * 4 + lhi) ^ rsw) * 16));
#pragma unroll
    for (int n = 0; n < 4; ++n)
#pragma unroll
      for (int kk = 0; kk < 2; ++kk)
        bfv[n][kk] = *reinterpret_cast<const bf16x8*>(
            (const char*)Bs + (wc * 64 + n * 16 + l15) * 128 + (((kk * 4 + lhi) ^ rsw) * 16));
#pragma unroll
    for (int m = 0; m < 4; ++m)
#pragma unroll
      for (int n = 0; n < 4; ++n)
#pragma unroll
        for (int kk = 0; kk < 2; ++kk)
          acc[m][n] = MFMA16(af[m][kk], bfv[n][kk], acc[m][n]);
    __syncthreads();
  }

  // epilogue: D layout col = lane&15, row = (lane>>4)*4 + j
#pragma unroll
  for (int n = 0; n < 4; ++n) {
    const int col = nbase + wc * 64 + n * 16 + l15;
    const int seg  = col >> 10;      // 0=Q 1=K 2=V (uniform per block)
    const int ncol = col & 1023;
    const float* bias = (seg == 0) ? bias0 : (seg == 1) ? bias1 : bias2;
    const float bv_ = bias[ncol];
    const int h = ncol >> 6, dk = ncol & 63;
    if (seg == 2) {
      // V: pack 4 consecutive t (j=0..3) into one 8B store
#pragma unroll
      for (int m = 0; m < 4; ++m) {
        const int t0 = mbase + wr * 64 + m * 16 + lhi * 4;  // multiple of 4
        const int b = t0 >> 11, t = t0 & 2047;
        union { ushort u[4]; uint2 v; } pk;
#pragma unroll
        for (int j = 0; j < 4; ++j) pk.u[j] = f2bu(acc[m][n][j] + bv_);
        *reinterpret_cast<uint2*>(&Vt[((size_t)(b * H_ + h) * DK_ + dk) * T_ + t]) = pk.v;
      }
    } else {
#pragma unroll
      for (int m = 0; m < 4; ++m) {
#pragma unroll
        for (int j = 0; j < 4; ++j) {
          const int row = mbase + wr * 64 + m * 16 + lhi * 4 + j;
          const int b = row >> 11, t = row & 2047;
          const int bh = b * H_ + h;
          float outv = acc[m][n][j] + bv_;
          if (seg == 0) outv *= SCALE_Q;  // fold 1/sqrt(dk)*log2(e) into Q
          const bf16 hv = __float2bfloat16(outv);
          if (seg == 0) Qb[((size_t)bh * T_ + t) * DK_ + dk] = hv;
          else          Kb[((size_t)bh * T_ + t) * DK_ + dk] = hv;
        }
      }
    }
  }
}

// ---------------- out GEMM: 64x64 tile, BK=64, 4 waves (2x2 of 32x32) ----------------
// out[4096][1024] = A @ Wot^T + bias ; grid (16, 64) = 1024 blocks -> 4 blocks/CU
// (was 128x64 @ 2 blocks/CU: too little TLP to hide ds_read+barrier; m114 wave-level
// overlap needs more resident waves). Same verified swizzled addressing.
__global__ __launch_bounds__(256, 4) void gemm_out_kernel(
    const bf16* __restrict__ A, const bf16* __restrict__ Bt,
    const float* __restrict__ bias, float* __restrict__ outp) {
  __shared__ __align__(16) bf16 As[64 * 64];  // 8 KB
  __shared__ __align__(16) bf16 Bs[64 * 64];  // 8 KB
  const int tid  = threadIdx.x;
  const int lane = tid & 63, wid = tid >> 6;
  const int wr = wid >> 1, wc = wid & 1;
  const int l15 = lane & 15, lhi = lane >> 4;
  const int mbase = blockIdx.y * 64, nbase = blockIdx.x * 64;

  f32x4 acc[2][2] = {};

  // staging: 64 rows x 8 chunks = 512 chunks per matrix; 256 threads x 2 each.
  const bf16* sa0; const bf16* sa1; const bf16* sb0; const bf16* sb1;
  {
    const int i0 = tid, i1 = 256 + tid;
    sa0 = A  + (size_t)(mbase + (i0 >> 3)) * D_ + (((i0 & 7) ^ ((i0 >> 3) & 7)) * 8);
    sa1 = A  + (size_t)(mbase + (i1 >> 3)) * D_ + (((i1 & 7) ^ ((i1 >> 3) & 7)) * 8);
    sb0 = Bt + (size_t)(nbase + (i0 >> 3)) * D_ + (((i0 & 7) ^ ((i0 >> 3) & 7)) * 8);
    sb1 = Bt + (size_t)(nbase + (i1 >> 3)) * D_ + (((i1 & 7) ^ ((i1 >> 3) & 7)) * 8);
  }
  const int ub = wid * 1024;  // wave-uniform LDS byte base per 256-chunk group

  for (int kt = 0; kt < D_; kt += 64) {
    gld_lds16(sa0 + kt, (char*)As + ub);
    gld_lds16(sa1 + kt, (char*)As + 4096 + ub);
    gld_lds16(sb0 + kt, (char*)Bs + ub);
    gld_lds16(sb1 + kt, (char*)Bs + 4096 + ub);
    __syncthreads();

    const int rsw = l15 & 7;
    bf16x8 af[2][2], bfv[2][2];
#pragma unroll
    for (int m = 0; m < 2; ++m)
#pragma unroll
      for (int kk = 0; kk < 2; ++kk)
        af[m][kk] = *reinterpret_cast<const bf16x8*>(
            (const char*)As + (wr * 32 + m * 16 + l15) * 128 + (((kk * 4 + lhi) ^ rsw) * 16));
#pragma unroll
    for (int n = 0; n < 2; ++n)
#pragma unroll
      for (int kk = 0; kk < 2; ++kk)
        bfv[n][kk] = *reinterpret_cast<const bf16x8*>(
            (const char*)Bs + (wc * 32 + n * 16 + l15) * 128 + (((kk * 4 + lhi) ^ rsw) * 16));
#pragma unroll
    for (int m = 0; m < 2; ++m)
#pragma unroll
      for (int n = 0; n < 2; ++n)
#pragma unroll
        for (int kk = 0; kk < 2; ++kk)
          acc[m][n] = MFMA16(af[m][kk], bfv[n][kk], acc[m][n]);
    __syncthreads();
  }

#pragma unroll
  for (int n = 0; n < 2; ++n) {
    const int col = nbase + wc * 32 + n * 16 + l15;
    const float bv_ = bias[col];
#pragma unroll
    for (int m = 0; m < 2; ++m)
#pragma unroll
      for (int j = 0; j < 4; ++j) {
        const int row = mbase + wr * 32 + m * 16 + lhi * 4 + j;
        outp[(size_t)row * D_ + col] = acc[m][n][j] + bv_;
      }
  }
}

// ---------------- flash attention (causal): 8-wave blocks, KV=128 per round ----------------
// Round-15-verified structure. Block = 8 waves (512 thr). Intra-block causal pairing:
// waves 0-3 own q-tile p, waves 4-7 own q-tile 31-p (64-row tiles). Each round stages
// a 128-wide K/V slab. V ds_reads issued EARLY (T14). Staging addresses HOISTED;
// softmax exp2 via raw v_exp_f32; defer-max (T13, THR=8). SWAPPED S^T = mfma(K,Q);
// P A-fragments built in registers (cvt_pk + shfl_xor(16)), kv-chunk permutation
// pi(lhi)=bitswap applied to P and V fragments. K LDS [128 rows][8 chunks] slot
// c^(r&7); V LDS [64 rows][16 chunks] slot c^(r&15). T5: setprio around MFMA.
__global__ __launch_bounds__(512, 4) void attn_kernel(const bf16* __restrict__ Q,
                                                      const bf16* __restrict__ Kg,
                                                      const bf16* __restrict__ Vt,
                                                      bf16* __restrict__ Mg) {
  __shared__ __align__(16) bf16 Kl[2][128 * 64];
  __shared__ __align__(16) bf16 Vl[2][64 * 128];
  const int tid = threadIdx.x, lane = tid & 63, wid = tid >> 6;
  const int l15 = lane & 15, lhi = lane >> 4;
  const int p  = blockIdx.x & 15;             // complementary q-tile pair index
  const int bh = blockIdx.x >> 4;             // adjacent bids share bh -> K/V L2 locality
  const int half = wid >> 2, w4 = wid & 3;
  const int qtile = half ? (31 - p) : p;
  const int qbase = qtile * 64 + w4 * 16;
  const int b = bh >> 4, h = bh & 15;

  const bf16* Qp = Q  + (size_t)bh * T_ * DK_;
  const bf16* Kp = Kg + (size_t)bh * T_ * DK_;
  const bf16* Vp = Vt + (size_t)bh * DK_ * T_;

  const bf16x8 qf0 = *reinterpret_cast<const bf16x8*>(&Qp[(size_t)(qbase + l15) * DK_ + lhi * 8]);
  const bf16x8 qf1 = *reinterpret_cast<const bf16x8*>(&Qp[(size_t)(qbase + l15) * DK_ + 32 + lhi * 8]);

  bf16x8 onesb;
#pragma unroll
  for (int i = 0; i < 8; ++i) onesb[i] = (__bf16)1.0f;

  f32x4 o[4] = {};
  f32x4 lacc = {};
  float mrow = -1e30f;  // running max for this lane's q-row (q = qbase + l15)

  const int ntr = (33 - p) >> 1;  // 128-wide rounds covering high tile's causal extent

  // hoisted per-thread staging sources (T2 pre-swizzle folded in once)
  const int iA = tid, iB = 512 + tid;
  const bf16* ks0 = Kp + (size_t)(iA >> 3) * DK_ + (((iA & 7) ^ ((iA >> 3) & 7)) * 8);
  const bf16* ks1 = Kp + (size_t)(iB >> 3) * DK_ + (((iB & 7) ^ ((iB >> 3) & 7)) * 8);
  const bf16* vs0 = Vp + (size_t)(iA >> 4) * T_ + (((iA & 15) ^ ((iA >> 4) & 15)) * 8);
  const bf16* vs1 = Vp + (size_t)(iB >> 4) * T_ + (((iB & 15) ^ ((iB >> 4) & 15)) * 8);
  const int ub0 = wid * 1024;           // wave-uniform LDS byte base, it=0
  const int ub1 = 8192 + wid * 1024;    // it=1

  // stage round 0 into buffer 0
  gld_lds16(ks0, (char*)Kl[0] + ub0);
  gld_lds16(ks1, (char*)Kl[0] + ub1);
  gld_lds16(vs0, (char*)Vl[0] + ub0);
  gld_lds16(vs1, (char*)Vl[0] + ub1);
  ks0 += 128 * DK_; ks1 += 128 * DK_; vs0 += 128; vs1 += 128;
  __syncthreads();

  for (int rnd = 0; rnd < ntr; ++rnd) {
    const int cur = rnd & 1;
    const char* Kb_ = cur ? (const char*)Kl[1] : (const char*)Kl[0];
    const char* Vb_ = cur ? (const char*)Vl[1] : (const char*)Vl[0];
    if (rnd + 1 < ntr) {  // stage next slab into the other buffer
      char* Kn = cur ? (char*)Kl[0] : (char*)Kl[1];
      char* Vn = cur ? (char*)Vl[0] : (char*)Vl[1];
      gld_lds16(ks0, Kn + ub0);
      gld_lds16(ks1, Kn + ub1);
      gld_lds16(vs0, Vn + ub0);
      gld_lds16(vs1, Vn + ub1);
      ks0 += 128 * DK_; ks1 += 128 * DK_; vs0 += 128; vs1 += 128;
    }

#pragma unroll
    for (int sub = 0; sub < 2; ++sub) {
      const int kv0 = rnd * 128 + sub * 64;
      if (kv0 <= qbase + 15) {  // wave-uniform: wave has live columns in this sub-tile
        // ---- S^T = K Q^T : lane holds q=l15; rows kv = kv0 + s*16 + lhi*4 + j
        f32x4 sv[4];
        __builtin_amdgcn_s_setprio(1);
#pragma unroll
        for (int s = 0; s < 4; ++s) {
          const int cbase = kv0 + s * 16;
          if (cbase <= qbase + 15) {
            const int row = sub * 64 + s * 16 + l15;  // row & 7 == l15 & 7
            const int rsw = l15 & 7;
            const bf16x8 k0 = *reinterpret_cast<const bf16x8*>(Kb_ + row * 128 + ((lhi       ^ rsw) * 16));
            const bf16x8 k1 = *reinterpret_cast<const bf16x8*>(Kb_ + row * 128 + (((4 + lhi) ^ rsw) * 16));
            f32x4 z = {};
            z = MFMA16(k0, qf0, z);          // swapped operand order
            sv[s] = MFMA16(k1, qf1, z);
          } else {
#pragma unroll
            for (int j = 0; j < 4; ++j) sv[s][j] = -1e30f;
          }
        }
        __builtin_amdgcn_s_setprio(0);

        // ---- V fragments from LDS, ISSUED EARLY (latency hides under softmax).
        // kv-chunk permutation pi(lhi) applied (matches P fragment build below).
        const int pl = ((lhi & 1) << 1) | (lhi >> 1);
        bf16x8 vf[8];
#pragma unroll
        for (int d = 0; d < 4; ++d) {
          const int rowv = d * 16 + l15;  // rowv & 15 == l15
#pragma unroll
          for (int s2 = 0; s2 < 2; ++s2) {
            const int cread = sub * 8 + s2 * 4 + pl;
            vf[d * 2 + s2] = *reinterpret_cast<const bf16x8*>(
                Vb_ + rowv * 256 + ((cread ^ l15) * 16));
          }
        }

        // ---- causal mask (kv = row, q = col): only the diagonal-straddling s-tile
#pragma unroll
        for (int s = 0; s < 4; ++s) {
          const int cbase = kv0 + s * 16;
          if (cbase <= qbase + 15 && cbase + 15 > qbase) {
            const int r = qbase + l15;
#pragma unroll
            for (int j = 0; j < 4; ++j) {
              const int c = cbase + lhi * 4 + j;
              sv[s][j] = (c <= r) ? sv[s][j] : -1e30f;
            }
          }
        }

        // ---- online softmax (exp2 domain), defer-max (T13): in-lane max only
        float ml = sv[0][0];
#pragma unroll
        for (int s = 0; s < 4; ++s)
#pragma unroll
          for (int j = 0; j < 4; ++j) ml = fmaxf(ml, sv[s][j]);

        if (__any(ml > mrow + 8.0f)) {
          float mx = ml;
          mx = fmaxf(mx, __shfl_xor(mx, 16, 64));
          mx = fmaxf(mx, __shfl_xor(mx, 32, 64));
          const float mn = fmaxf(mrow, mx);
          const float sc = FEXP2(mrow - mn);
          mrow = mn;
          // broadcast sc into O-layout rows: row q' = lhi*4 + j lives in lane q'
          const int sci = __float_as_int(sc);
#pragma unroll
          for (int j = 0; j < 4; ++j) {
            const float scj = __int_as_float(
                __builtin_amdgcn_ds_bpermute((lhi * 4 + j) * 4, sci));
            lacc[j] *= scj;
            o[0][j] *= scj; o[1][j] *= scj; o[2][j] *= scj; o[3][j] *= scj;
          }
        }
#pragma unroll
        for (int s = 0; s < 4; ++s)
#pragma unroll
          for (int j = 0; j < 4; ++j) sv[s][j] = FEXP2(sv[s][j] - mrow);

        // ---- P A-fragments in registers (no LDS round-trip).
        // Lane's k-slot chunk holds kv chunk pi(lhi), pi = [0,2,1,3] (bitswap).
        const bool oddl = (lhi & 1) != 0;
        bf16x8 pf[2];
#pragma unroll
        for (int hh = 0; hh < 2; ++hh) {
          const uint32_t u0l = cvtpk_bf16(sv[2 * hh][0], sv[2 * hh][1]);
          const uint32_t u0h = cvtpk_bf16(sv[2 * hh][2], sv[2 * hh][3]);
          const uint32_t u1l = cvtpk_bf16(sv[2 * hh + 1][0], sv[2 * hh + 1][1]);
          const uint32_t u1h = cvtpk_bf16(sv[2 * hh + 1][2], sv[2 * hh + 1][3]);
          const uint32_t sl = oddl ? u0l : u1l;
          const uint32_t sh = oddl ? u0h : u1h;
          const uint32_t rl = (uint32_t)__shfl_xor((int)sl, 16, 64);
          const uint32_t rh = (uint32_t)__shfl_xor((int)sh, 16, 64);
          union { uint32_t w[4]; bf16x8 v; } fr;
          fr.w[0] = oddl ? rl : u0l;
          fr.w[1] = oddl ? rh : u0h;
          fr.w[2] = oddl ? u1l : rl;
          fr.w[3] = oddl ? u1h : rh;
          pf[hh] = fr.v;
        }

        // ---- O += P V ; row-sums l += P 1 (same C layout & rescale as O)
        __builtin_amdgcn_s_setprio(1);
#pragma unroll
        for (int d = 0; d < 4; ++d) {
          o[d] = MFMA16(pf[0], vf[d * 2 + 0], o[d]);
          o[d] = MFMA16(pf[1], vf[d * 2 + 1], o[d]);
        }
        lacc = MFMA16(pf[0], onesb, lacc);
        lacc = MFMA16(pf[1], onesb, lacc);
        __builtin_amdgcn_s_setprio(0);
      }
    }

    __syncthreads();  // drains vmcnt (next slab staged) + orders buffer reuse
  }

#pragma unroll
  for (int j = 0; j < 4; ++j) {
    const float inv = 1.0f / lacc[j];
    const int tq = qbase + lhi * 4 + j;
#pragma unroll
    for (int d = 0; d < 4; ++d)
      Mg[((size_t)b * T_ + tq) * D_ + h * DK_ + d * 16 + l15] = __float2bfloat16(o[d][j] * inv);
  }
}

// ---------------- launch ----------------
extern "C" void kernel_launch(void* const* d_in, const int* in_sizes, int n_in,
                              void* d_out, int out_size, void* d_ws, size_t ws_size,
                              hipStream_t stream) {
  (void)in_sizes; (void)n_in; (void)out_size; (void)ws_size;
  const float* x  = (const float*)d_in[0];
  const float* Wq = (const float*)d_in[1];
  const float* bq = (const float*)d_in[2];
  const float* Wk = (const float*)d_in[3];
  const float* bk = (const float*)d_in[4];
  const float* Wv = (const float*)d_in[5];
  const float* bv = (const float*)d_in[6];
  const float* Wo = (const float*)d_in[7];
  const float* bo = (const float*)d_in[8];
  float* out = (float*)d_out;

  // workspace layout (40 MB): Mg aliases xb (xb dead after QKV GEMM, attn runs after)
  char* ws = (char*)d_ws;
  bf16* xb  = (bf16*)(ws);                       // 8 MB [4096][1024]
  bf16* Mg  = (bf16*)(ws);                       // 8 MB [4096][1024] (alias, written by attn)
  bf16* Wt  = (bf16*)(ws + (size_t)( 8u << 20)); // 6 MB [3072][1024] (Wq|Wk|Wv transposed)
  bf16* Wot = (bf16*)(ws + (size_t)(14u << 20)); // 2 MB [1024][1024] (Wo transposed)
  bf16* Qb  = (bf16*)(ws + (size_t)(16u << 20)); // 8 MB [32][2048][64]
  bf16* Kb  = (bf16*)(ws + (size_t)(24u << 20)); // 8 MB [32][2048][64]
  bf16* Vt  = (bf16*)(ws + (size_t)(32u << 20)); // 8 MB [32][64][2048]

  pack_all_kernel<<<5120, 256, 0, stream>>>(x, Wq, Wk, Wv, Wo, xb, Wt, Wot);
  // fused QKV: C[4096][3072] = xb @ [Wq|Wk|Wv]
  gemm_qkv_kernel<<<dim3(24, 32), 256, 0, stream>>>(xb, Wt, bq, bk, bv, Qb, Kb, Vt);
  attn_kernel<<<dim3(512), 512, 0, stream>>>(Qb, Kb, Vt, Mg);
  // out[4096][1024] = Mg @ Wo + bo
  gemm_out_kernel<<<dim3(16, 64), 256, 0, stream>>>(Mg, Wot, bo, out);
}

// Round 19
// 93.708 us; speedup vs baseline: 1.2603x; 1.0341x over previous
//
#include <hip/hip_runtime.h>
#include <hip/hip_bf16.h>
#include <cstdint>
#include <cstddef>

// MHA forward: B=2, T=2048, D=1024, H=16, dk=64. fp32 in/out, bf16 MFMA internal.
#define B_  2
#define T_  2048
#define D_  1024
#define H_  16
#define DK_ 64

typedef __hip_bfloat16 bf16;
typedef __bf16 bf16x8 __attribute__((ext_vector_type(8)));  // MFMA A/B frag (4 VGPRs)
typedef float  f32x4  __attribute__((ext_vector_type(4)));  // MFMA C/D frag

#define MFMA16(a, b, c) __builtin_amdgcn_mfma_f32_16x16x32_bf16((a), (b), (c), 0, 0, 0)

// Q production scale: 1/sqrt(64) * log2(e)  (softmax done in exp2 domain)
#define SCALE_Q 0.1803368801111137f

// fast exp2: raw v_exp_f32 (no denorm fixup; inputs are either ~[-30,8] or -inf-ish)
#if defined(__has_builtin)
#if __has_builtin(__builtin_amdgcn_exp2f)
#define FEXP2(x) __builtin_amdgcn_exp2f(x)
#endif
#endif
#ifndef FEXP2
__device__ static inline float fexp2_asm(float x) {
  float r; asm("v_exp_f32 %0, %1" : "=v"(r) : "v"(x)); return r;
}
#define FEXP2(x) fexp2_asm(x)
#endif

__device__ static inline void gld_lds16(const void* g, void* l) {
  // async global->LDS, 16B per lane; LDS dest is wave-uniform base + lane*16
  __builtin_amdgcn_global_load_lds((const __attribute__((address_space(1))) void*)g,
                                   (__attribute__((address_space(3))) void*)l, 16, 0, 0);
}

__device__ static inline ushort f2bu(float x) {
  union { bf16 h; ushort u; } c;
  c.h = __float2bfloat16(x);
  return c.u;
}

__device__ static inline uint32_t cvtpk_bf16(float lo, float hi) {
  uint32_t r;
  asm volatile("v_cvt_pk_bf16_f32 %0, %1, %2" : "=v"(r) : "v"(lo), "v"(hi));
  return r;  // low16 = bf16(lo), high16 = bf16(hi)
}

// ---------------- fused pack: x fp32->bf16 (bids 0..4095) + W transpose (bids 4096..5119) ----------------
__global__ __launch_bounds__(256) void pack_all_kernel(const float* __restrict__ x,
                                                       const float* __restrict__ Wq,
                                                       const float* __restrict__ Wk,
                                                       const float* __restrict__ Wv,
                                                       const float* __restrict__ Wo,
                                                       bf16* __restrict__ xb,
                                                       bf16* __restrict__ Wt,    // [3072][1024]
                                                       bf16* __restrict__ Wot) { // [1024][1024]
  __shared__ bf16 t[64][68];  // stride 68 (136B): 8B-aligned rows, 2-way bank alias (free)
  const int bid = blockIdx.x;
  const int tid = threadIdx.x;
  if (bid < 4096) {
    // ---- pack x: 4 fp32 -> 4 bf16 per thread
    const int i = bid * 256 + tid;
    const float4 v = reinterpret_cast<const float4*>(x)[i];
    union { ushort4 u; bf16 h[4]; } c;
    c.h[0] = __float2bfloat16(v.x);
    c.h[1] = __float2bfloat16(v.y);
    c.h[2] = __float2bfloat16(v.z);
    c.h[3] = __float2bfloat16(v.w);
    reinterpret_cast<ushort4*>(xb)[i] = c.u;
    return;
  }
  // ---- pack W: transpose+convert 64x64 tiles (vectorized: float4 reads, 8B stores)
  const int wb  = bid - 4096;
  const int mat  = wb >> 8;        // 0..3 : Wq,Wk,Wv,Wo
  const int tile = wb & 255;       // 16x16 tiles of 64x64
  const int tr = tile >> 4, tc = tile & 15;
  const float* W = (mat == 0) ? Wq : (mat == 1) ? Wk : (mat == 2) ? Wv : Wo;
#pragma unroll
  for (int i = 0; i < 4; ++i) {
    const int idx = i * 256 + tid;
    const int r = idx >> 4, c4 = (idx & 15) * 4;
    const float4 v = *reinterpret_cast<const float4*>(&W[(size_t)(tr * 64 + r) * D_ + tc * 64 + c4]);
    union { ushort u[4]; uint2 q; } pk;
    pk.u[0] = f2bu(v.x); pk.u[1] = f2bu(v.y); pk.u[2] = f2bu(v.z); pk.u[3] = f2bu(v.w);
    *reinterpret_cast<uint2*>(&t[r][c4]) = pk.q;
  }
  __syncthreads();
  bf16* dst = (mat == 3) ? Wot : (Wt + (size_t)mat * D_ * D_);
#pragma unroll
  for (int i = 0; i < 4; ++i) {
    const int idx = i * 256 + tid;
    const int n = idx >> 4, kg = (idx & 15) * 4;
    union { ushort u[4]; uint2 q; } pk;
#pragma unroll
    for (int j = 0; j < 4; ++j) pk.u[j] = reinterpret_cast<const ushort&>(t[kg + j][n]);
    *reinterpret_cast<uint2*>(&dst[(size_t)(tc * 64 + n) * D_ + tr * 64 + kg]) = pk.q;
  }
}

// ---------------- QKV GEMM: 128x128 bf16, BK=64, 4 waves (2x2 of 64x64) ----------------
// A: [M][K] row-major bf16.  Bt: [N][K] row-major bf16 (B transposed).
// BK=64 halves barrier count (16 rounds x 32 MFMA). LDS rows of 8x16B chunks,
// slot c^(r&7) (T2 swizzle via pre-swizzled source; reads XOR l15&7).
// Epilogue -> Qb/Kb [BH][T][64], Vt [BH][64][T] (V packed 4t/store), + bias;
// Q scaled by SCALE_Q.
__global__ __launch_bounds__(256, 3) void gemm_qkv_kernel(
    const bf16* __restrict__ A, const bf16* __restrict__ Bt,
    const float* __restrict__ bias0, const float* __restrict__ bias1,
    const float* __restrict__ bias2,
    bf16* __restrict__ Qb, bf16* __restrict__ Kb, bf16* __restrict__ Vt) {
  __shared__ __align__(16) bf16 As[128 * 64];  // 16 KB
  __shared__ __align__(16) bf16 Bs[128 * 64];  // 16 KB
  const int tid  = threadIdx.x;
  const int lane = tid & 63, wid = tid >> 6;
  const int wr = wid >> 1, wc = wid & 1;
  const int l15 = lane & 15, lhi = lane >> 4;
  const int mbase = blockIdx.y * 128, nbase = blockIdx.x * 128;

  f32x4 acc[4][4] = {};

  const bf16* sa[4]; const bf16* sb[4];
#pragma unroll
  for (int it = 0; it < 4; ++it) {
    const int idx = it * 256 + tid;
    const int r = idx >> 3, cs = ((idx & 7) ^ ((idx >> 3) & 7)) * 8;
    sa[it] = A  + (size_t)(mbase + r) * D_ + cs;
    sb[it] = Bt + (size_t)(nbase + r) * D_ + cs;
  }
  const int ub = wid * 1024;  // wave-uniform LDS byte base within each 256-chunk group

  for (int kt = 0; kt < D_; kt += 64) {
#pragma unroll
    for (int it = 0; it < 4; ++it) {
      gld_lds16(sa[it] + kt, (char*)As + it * 4096 + ub);
      gld_lds16(sb[it] + kt, (char*)Bs + it * 4096 + ub);
    }
    __syncthreads();  // compiler drains vmcnt before barrier

    const int rsw = l15 & 7;
    bf16x8 af[4][2], bfv[4][2];
#pragma unroll
    for (int m = 0; m < 4; ++m)
#pragma unroll
      for (int kk = 0; kk < 2; ++kk)
        af[m][kk] = *reinterpret_cast<const bf16x8*>(
            (const char*)As + (wr * 64 + m * 16 + l15) * 128 + (((kk * 4 + lhi) ^ rsw) * 16));
#pragma unroll
    for (int n = 0; n < 4; ++n)
#pragma unroll
      for (int kk = 0; kk < 2; ++kk)
        bfv[n][kk] = *reinterpret_cast<const bf16x8*>(
            (const char*)Bs + (wc * 64 + n * 16 + l15) * 128 + (((kk * 4 + lhi) ^ rsw) * 16));
#pragma unroll
    for (int m = 0; m < 4; ++m)
#pragma unroll
      for (int n = 0; n < 4; ++n)
#pragma unroll
        for (int kk = 0; kk < 2; ++kk)
          acc[m][n] = MFMA16(af[m][kk], bfv[n][kk], acc[m][n]);
    __syncthreads();
  }

  // epilogue: D layout col = lane&15, row = (lane>>4)*4 + j
#pragma unroll
  for (int n = 0; n < 4; ++n) {
    const int col = nbase + wc * 64 + n * 16 + l15;
    const int seg  = col >> 10;      // 0=Q 1=K 2=V (uniform per block)
    const int ncol = col & 1023;
    const float* bias = (seg == 0) ? bias0 : (seg == 1) ? bias1 : bias2;
    const float bv_ = bias[ncol];
    const int h = ncol >> 6, dk = ncol & 63;
    if (seg == 2) {
      // V: pack 4 consecutive t (j=0..3) into one 8B store
#pragma unroll
      for (int m = 0; m < 4; ++m) {
        const int t0 = mbase + wr * 64 + m * 16 + lhi * 4;  // multiple of 4
        const int b = t0 >> 11, t = t0 & 2047;
        union { ushort u[4]; uint2 v; } pk;
#pragma unroll
        for (int j = 0; j < 4; ++j) pk.u[j] = f2bu(acc[m][n][j] + bv_);
        *reinterpret_cast<uint2*>(&Vt[((size_t)(b * H_ + h) * DK_ + dk) * T_ + t]) = pk.v;
      }
    } else {
#pragma unroll
      for (int m = 0; m < 4; ++m) {
#pragma unroll
        for (int j = 0; j < 4; ++j) {
          const int row = mbase + wr * 64 + m * 16 + lhi * 4 + j;
          const int b = row >> 11, t = row & 2047;
          const int bh = b * H_ + h;
          float outv = acc[m][n][j] + bv_;
          if (seg == 0) outv *= SCALE_Q;  // fold 1/sqrt(dk)*log2(e) into Q
          const bf16 hv = __float2bfloat16(outv);
          if (seg == 0) Qb[((size_t)bh * T_ + t) * DK_ + dk] = hv;
          else          Kb[((size_t)bh * T_ + t) * DK_ + dk] = hv;
        }
      }
    }
  }
}

// ---------------- out GEMM: 64x64 tile, BK=64, 4 waves (2x2 of 32x32) ----------------
// out[4096][1024] = A @ Wot^T + bias ; grid (16, 64) = 1024 blocks -> 4 blocks/CU.
__global__ __launch_bounds__(256, 4) void gemm_out_kernel(
    const bf16* __restrict__ A, const bf16* __restrict__ Bt,
    const float* __restrict__ bias, float* __restrict__ outp) {
  __shared__ __align__(16) bf16 As[64 * 64];  // 8 KB
  __shared__ __align__(16) bf16 Bs[64 * 64];  // 8 KB
  const int tid  = threadIdx.x;
  const int lane = tid & 63, wid = tid >> 6;
  const int wr = wid >> 1, wc = wid & 1;
  const int l15 = lane & 15, lhi = lane >> 4;
  const int mbase = blockIdx.y * 64, nbase = blockIdx.x * 64;

  f32x4 acc[2][2] = {};

  // staging: 64 rows x 8 chunks = 512 chunks per matrix; 256 threads x 2 each.
  const bf16* sa0; const bf16* sa1; const bf16* sb0; const bf16* sb1;
  {
    const int i0 = tid, i1 = 256 + tid;
    sa0 = A  + (size_t)(mbase + (i0 >> 3)) * D_ + (((i0 & 7) ^ ((i0 >> 3) & 7)) * 8);
    sa1 = A  + (size_t)(mbase + (i1 >> 3)) * D_ + (((i1 & 7) ^ ((i1 >> 3) & 7)) * 8);
    sb0 = Bt + (size_t)(nbase + (i0 >> 3)) * D_ + (((i0 & 7) ^ ((i0 >> 3) & 7)) * 8);
    sb1 = Bt + (size_t)(nbase + (i1 >> 3)) * D_ + (((i1 & 7) ^ ((i1 >> 3) & 7)) * 8);
  }
  const int ub = wid * 1024;  // wave-uniform LDS byte base per 256-chunk group

  for (int kt = 0; kt < D_; kt += 64) {
    gld_lds16(sa0 + kt, (char*)As + ub);
    gld_lds16(sa1 + kt, (char*)As + 4096 + ub);
    gld_lds16(sb0 + kt, (char*)Bs + ub);
    gld_lds16(sb1 + kt, (char*)Bs + 4096 + ub);
    __syncthreads();

    const int rsw = l15 & 7;
    bf16x8 af[2][2], bfv[2][2];
#pragma unroll
    for (int m = 0; m < 2; ++m)
#pragma unroll
      for (int kk = 0; kk < 2; ++kk)
        af[m][kk] = *reinterpret_cast<const bf16x8*>(
            (const char*)As + (wr * 32 + m * 16 + l15) * 128 + (((kk * 4 + lhi) ^ rsw) * 16));
#pragma unroll
    for (int n = 0; n < 2; ++n)
#pragma unroll
      for (int kk = 0; kk < 2; ++kk)
        bfv[n][kk] = *reinterpret_cast<const bf16x8*>(
            (const char*)Bs + (wc * 32 + n * 16 + l15) * 128 + (((kk * 4 + lhi) ^ rsw) * 16));
#pragma unroll
    for (int m = 0; m < 2; ++m)
#pragma unroll
      for (int n = 0; n < 2; ++n)
#pragma unroll
        for (int kk = 0; kk < 2; ++kk)
          acc[m][n] = MFMA16(af[m][kk], bfv[n][kk], acc[m][n]);
    __syncthreads();
  }

#pragma unroll
  for (int n = 0; n < 2; ++n) {
    const int col = nbase + wc * 32 + n * 16 + l15;
    const float bv_ = bias[col];
#pragma unroll
    for (int m = 0; m < 2; ++m)
#pragma unroll
      for (int j = 0; j < 4; ++j) {
        const int row = mbase + wr * 32 + m * 16 + lhi * 4 + j;
        outp[(size_t)row * D_ + col] = acc[m][n][j] + bv_;
      }
  }
}

// ---------------- flash attention (causal): 8-wave blocks, KV=128 per round ----------------
// Round-15-verified inner structure. Block = 8 waves (512 thr). Intra-block causal
// pairing: waves 0-3 own q-tile p, waves 4-7 own q-tile 31-p (64-row tiles).
// NEW bid->(p,bh) map: q8=bid&255 -> p0=q8&7, bh=q8>>3; half=bid>>8 -> p = half?15-p0:p0.
// Round counts (33-p)>>1 of blocks c and c+256 sum to 25 for ALL c (complementary
// p0/15-p0), so co-resident blocks under round-robin dispatch have uniform total
// barrier/staging work -> kills the per-CU duration spread (tail). Same bh for the
// co-resident pair preserves K/V L2 sharing.
// V ds_reads issued EARLY (T14); staging addresses HOISTED; exp2 via raw v_exp_f32;
// defer-max (T13, THR=8). SWAPPED S^T = mfma(K,Q); P A-fragments in registers
// (cvt_pk + shfl_xor(16)), kv-chunk permutation pi(lhi)=bitswap on P and V.
// K LDS [128 rows][8 chunks] slot c^(r&7); V LDS [64 rows][16 chunks] slot c^(r&15).
// T5: setprio(1) around MFMA clusters.
__global__ __launch_bounds__(512, 4) void attn_kernel(const bf16* __restrict__ Q,
                                                      const bf16* __restrict__ Kg,
                                                      const bf16* __restrict__ Vt,
                                                      bf16* __restrict__ Mg) {
  __shared__ __align__(16) bf16 Kl[2][128 * 64];
  __shared__ __align__(16) bf16 Vl[2][64 * 128];
  const int tid = threadIdx.x, lane = tid & 63, wid = tid >> 6;
  const int l15 = lane & 15, lhi = lane >> 4;
  const int q8   = blockIdx.x & 255;
  const int hlf  = blockIdx.x >> 8;
  const int p0   = q8 & 7;
  const int p    = hlf ? (15 - p0) : p0;   // complementary q-tile pair index
  const int bh   = q8 >> 3;                // adjacent bids share bh -> K/V L2 locality
  const int half = wid >> 2, w4 = wid & 3;
  const int qtile = half ? (31 - p) : p;
  const int qbase = qtile * 64 + w4 * 16;
  const int b = bh >> 4, h = bh & 15;

  const bf16* Qp = Q  + (size_t)bh * T_ * DK_;
  const bf16* Kp = Kg + (size_t)bh * T_ * DK_;
  const bf16* Vp = Vt + (size_t)bh * DK_ * T_;

  const bf16x8 qf0 = *reinterpret_cast<const bf16x8*>(&Qp[(size_t)(qbase + l15) * DK_ + lhi * 8]);
  const bf16x8 qf1 = *reinterpret_cast<const bf16x8*>(&Qp[(size_t)(qbase + l15) * DK_ + 32 + lhi * 8]);

  bf16x8 onesb;
#pragma unroll
  for (int i = 0; i < 8; ++i) onesb[i] = (__bf16)1.0f;

  f32x4 o[4] = {};
  f32x4 lacc = {};
  float mrow = -1e30f;  // running max for this lane's q-row (q = qbase + l15)

  const int ntr = (33 - p) >> 1;  // 128-wide rounds covering high tile's causal extent

  // hoisted per-thread staging sources (T2 pre-swizzle folded in once)
  const int iA = tid, iB = 512 + tid;
  const bf16* ks0 = Kp + (size_t)(iA >> 3) * DK_ + (((iA & 7) ^ ((iA >> 3) & 7)) * 8);
  const bf16* ks1 = Kp + (size_t)(iB >> 3) * DK_ + (((iB & 7) ^ ((iB >> 3) & 7)) * 8);
  const bf16* vs0 = Vp + (size_t)(iA >> 4) * T_ + (((iA & 15) ^ ((iA >> 4) & 15)) * 8);
  const bf16* vs1 = Vp + (size_t)(iB >> 4) * T_ + (((iB & 15) ^ ((iB >> 4) & 15)) * 8);
  const int ub0 = wid * 1024;           // wave-uniform LDS byte base, it=0
  const int ub1 = 8192 + wid * 1024;    // it=1

  // stage round 0 into buffer 0
  gld_lds16(ks0, (char*)Kl[0] + ub0);
  gld_lds16(ks1, (char*)Kl[0] + ub1);
  gld_lds16(vs0, (char*)Vl[0] + ub0);
  gld_lds16(vs1, (char*)Vl[0] + ub1);
  ks0 += 128 * DK_; ks1 += 128 * DK_; vs0 += 128; vs1 += 128;
  __syncthreads();

  for (int rnd = 0; rnd < ntr; ++rnd) {
    const int cur = rnd & 1;
    const char* Kb_ = cur ? (const char*)Kl[1] : (const char*)Kl[0];
    const char* Vb_ = cur ? (const char*)Vl[1] : (const char*)Vl[0];
    if (rnd + 1 < ntr) {  // stage next slab into the other buffer
      char* Kn = cur ? (char*)Kl[0] : (char*)Kl[1];
      char* Vn = cur ? (char*)Vl[0] : (char*)Vl[1];
      gld_lds16(ks0, Kn + ub0);
      gld_lds16(ks1, Kn + ub1);
      gld_lds16(vs0, Vn + ub0);
      gld_lds16(vs1, Vn + ub1);
      ks0 += 128 * DK_; ks1 += 128 * DK_; vs0 += 128; vs1 += 128;
    }

#pragma unroll
    for (int sub = 0; sub < 2; ++sub) {
      const int kv0 = rnd * 128 + sub * 64;
      if (kv0 <= qbase + 15) {  // wave-uniform: wave has live columns in this sub-tile
        // ---- S^T = K Q^T : lane holds q=l15; rows kv = kv0 + s*16 + lhi*4 + j
        f32x4 sv[4];
        __builtin_amdgcn_s_setprio(1);
#pragma unroll
        for (int s = 0; s < 4; ++s) {
          const int cbase = kv0 + s * 16;
          if (cbase <= qbase + 15) {
            const int row = sub * 64 + s * 16 + l15;  // row & 7 == l15 & 7
            const int rsw = l15 & 7;
            const bf16x8 k0 = *reinterpret_cast<const bf16x8*>(Kb_ + row * 128 + ((lhi       ^ rsw) * 16));
            const bf16x8 k1 = *reinterpret_cast<const bf16x8*>(Kb_ + row * 128 + (((4 + lhi) ^ rsw) * 16));
            f32x4 z = {};
            z = MFMA16(k0, qf0, z);          // swapped operand order
            sv[s] = MFMA16(k1, qf1, z);
          } else {
#pragma unroll
            for (int j = 0; j < 4; ++j) sv[s][j] = -1e30f;
          }
        }
        __builtin_amdgcn_s_setprio(0);

        // ---- V fragments from LDS, ISSUED EARLY (latency hides under softmax).
        // kv-chunk permutation pi(lhi) applied (matches P fragment build below).
        const int pl = ((lhi & 1) << 1) | (lhi >> 1);
        bf16x8 vf[8];
#pragma unroll
        for (int d = 0; d < 4; ++d) {
          const int rowv = d * 16 + l15;  // rowv & 15 == l15
#pragma unroll
          for (int s2 = 0; s2 < 2; ++s2) {
            const int cread = sub * 8 + s2 * 4 + pl;
            vf[d * 2 + s2] = *reinterpret_cast<const bf16x8*>(
                Vb_ + rowv * 256 + ((cread ^ l15) * 16));
          }
        }

        // ---- causal mask (kv = row, q = col): only the diagonal-straddling s-tile
#pragma unroll
        for (int s = 0; s < 4; ++s) {
          const int cbase = kv0 + s * 16;
          if (cbase <= qbase + 15 && cbase + 15 > qbase) {
            const int r = qbase + l15;
#pragma unroll
            for (int j = 0; j < 4; ++j) {
              const int c = cbase + lhi * 4 + j;
              sv[s][j] = (c <= r) ? sv[s][j] : -1e30f;
            }
          }
        }

        // ---- online softmax (exp2 domain), defer-max (T13): in-lane max only
        float ml = sv[0][0];
#pragma unroll
        for (int s = 0; s < 4; ++s)
#pragma unroll
          for (int j = 0; j < 4; ++j) ml = fmaxf(ml, sv[s][j]);

        if (__any(ml > mrow + 8.0f)) {
          float mx = ml;
          mx = fmaxf(mx, __shfl_xor(mx, 16, 64));
          mx = fmaxf(mx, __shfl_xor(mx, 32, 64));
          const float mn = fmaxf(mrow, mx);
          const float sc = FEXP2(mrow - mn);
          mrow = mn;
          // broadcast sc into O-layout rows: row q' = lhi*4 + j lives in lane q'
          const int sci = __float_as_int(sc);
#pragma unroll
          for (int j = 0; j < 4; ++j) {
            const float scj = __int_as_float(
                __builtin_amdgcn_ds_bpermute((lhi * 4 + j) * 4, sci));
            lacc[j] *= scj;
            o[0][j] *= scj; o[1][j] *= scj; o[2][j] *= scj; o[3][j] *= scj;
          }
        }
#pragma unroll
        for (int s = 0; s < 4; ++s)
#pragma unroll
          for (int j = 0; j < 4; ++j) sv[s][j] = FEXP2(sv[s][j] - mrow);

        // ---- P A-fragments in registers (no LDS round-trip).
        // Lane's k-slot chunk holds kv chunk pi(lhi), pi = [0,2,1,3] (bitswap).
        const bool oddl = (lhi & 1) != 0;
        bf16x8 pf[2];
#pragma unroll
        for (int hh = 0; hh < 2; ++hh) {
          const uint32_t u0l = cvtpk_bf16(sv[2 * hh][0], sv[2 * hh][1]);
          const uint32_t u0h = cvtpk_bf16(sv[2 * hh][2], sv[2 * hh][3]);
          const uint32_t u1l = cvtpk_bf16(sv[2 * hh + 1][0], sv[2 * hh + 1][1]);
          const uint32_t u1h = cvtpk_bf16(sv[2 * hh + 1][2], sv[2 * hh + 1][3]);
          const uint32_t sl = oddl ? u0l : u1l;
          const uint32_t sh = oddl ? u0h : u1h;
          const uint32_t rl = (uint32_t)__shfl_xor((int)sl, 16, 64);
          const uint32_t rh = (uint32_t)__shfl_xor((int)sh, 16, 64);
          union { uint32_t w[4]; bf16x8 v; } fr;
          fr.w[0] = oddl ? rl : u0l;
          fr.w[1] = oddl ? rh : u0h;
          fr.w[2] = oddl ? u1l : rl;
          fr.w[3] = oddl ? u1h : rh;
          pf[hh] = fr.v;
        }

        // ---- O += P V ; row-sums l += P 1 (same C layout & rescale as O)
        __builtin_amdgcn_s_setprio(1);
#pragma unroll
        for (int d = 0; d < 4; ++d) {
          o[d] = MFMA16(pf[0], vf[d * 2 + 0], o[d]);
          o[d] = MFMA16(pf[1], vf[d * 2 + 1], o[d]);
        }
        lacc = MFMA16(pf[0], onesb, lacc);
        lacc = MFMA16(pf[1], onesb, lacc);
        __builtin_amdgcn_s_setprio(0);
      }
    }

    __syncthreads();  // drains vmcnt (next slab staged) + orders buffer reuse
  }

#pragma unroll
  for (int j = 0; j < 4; ++j) {
    const float inv = 1.0f / lacc[j];
    const int tq = qbase + lhi * 4 + j;
#pragma unroll
    for (int d = 0; d < 4; ++d)
      Mg[((size_t)b * T_ + tq) * D_ + h * DK_ + d * 16 + l15] = __float2bfloat16(o[d][j] * inv);
  }
}

// ---------------- launch ----------------
extern "C" void kernel_launch(void* const* d_in, const int* in_sizes, int n_in,
                              void* d_out, int out_size, void* d_ws, size_t ws_size,
                              hipStream_t stream) {
  (void)in_sizes; (void)n_in; (void)out_size; (void)ws_size;
  const float* x  = (const float*)d_in[0];
  const float* Wq = (const float*)d_in[1];
  const float* bq = (const float*)d_in[2];
  const float* Wk = (const float*)d_in[3];
  const float* bk = (const float*)d_in[4];
  const float* Wv = (const float*)d_in[5];
  const float* bv = (const float*)d_in[6];
  const float* Wo = (const float*)d_in[7];
  const float* bo = (const float*)d_in[8];
  float* out = (float*)d_out;

  // workspace layout (40 MB): Mg aliases xb (xb dead after QKV GEMM, attn runs after)
  char* ws = (char*)d_ws;
  bf16* xb  = (bf16*)(ws);                       // 8 MB [4096][1024]
  bf16* Mg  = (bf16*)(ws);                       // 8 MB [4096][1024] (alias, written by attn)
  bf16* Wt  = (bf16*)(ws + (size_t)( 8u << 20)); // 6 MB [3072][1024] (Wq|Wk|Wv transposed)
  bf16* Wot = (bf16*)(ws + (size_t)(14u << 20)); // 2 MB [1024][1024] (Wo transposed)
  bf16* Qb  = (bf16*)(ws + (size_t)(16u << 20)); // 8 MB [32][2048][64]
  bf16* Kb  = (bf16*)(ws + (size_t)(24u << 20)); // 8 MB [32][2048][64]
  bf16* Vt  = (bf16*)(ws + (size_t)(32u << 20)); // 8 MB [32][64][2048]

  pack_all_kernel<<<5120, 256, 0, stream>>>(x, Wq, Wk, Wv, Wo, xb, Wt, Wot);
  // fused QKV: C[4096][3072] = xb @ [Wq|Wk|Wv]
  gemm_qkv_kernel<<<dim3(24, 32), 256, 0, stream>>>(xb, Wt, bq, bk, bv, Qb, Kb, Vt);
  attn_kernel<<<dim3(512), 512, 0, stream>>>(Qb, Kb, Vt, Mg);
  // out[4096][1024] = Mg @ Wo + bo
  gemm_out_kernel<<<dim3(16, 64), 256, 0, stream>>>(Mg, Wot, bo, out);
}